// Round 1
// baseline (5213.754 us; speedup 1.0000x reference)
//
#include <hip/hip_runtime.h>
#include <hip/hip_bf16.h>

typedef _Float16 f16;
typedef _Float16 f16x8 __attribute__((ext_vector_type(8)));
typedef float f32x4 __attribute__((ext_vector_type(4)));

#define B_ 8
#define S_ 512
#define H_ 768
#define V_ 35004
#define J_ 30
#define K_ 9
#define R_ 2160          // B*J*K rows, row r = b*270 + j*9 + t  (matches out layout)
#define H3 2304
#define NBLK 96

// ---------------------------------------------------------------- prep kernels

__global__ void k_zero_cnt(int* cnt) {
    for (int i = threadIdx.x; i < 270; i += 256) cnt[i] = 0;
}

__global__ void k_cast(const float* __restrict__ s, f16* __restrict__ d, long n) {
    for (long i = (long)blockIdx.x * 256 + threadIdx.x; i < n; i += (long)gridDim.x * 256)
        d[i] = (f16)s[i];
}

// W_all[r] = (t==0) ? decoder_input[b,j,:] : embed[teacher[b,j,t-1],:]
__global__ void k_build_wall(const float* __restrict__ emb, const float* __restrict__ dec,
                             const int* __restrict__ teacher, f16* __restrict__ Wall) {
    int r = blockIdx.x;
    int b = r / 270, s = r % 270, j = s / 9, t = s % 9;
    const float* src = (t == 0) ? dec + ((long)b * J_ + j) * H_
                                : emb + (long)teacher[((long)b * J_ + j) * K_ + (t - 1)] * H_;
    f16* dst = Wall + (long)r * H_;
    for (int c = threadIdx.x; c < H_; c += 256) dst[c] = (f16)src[c];
}

// enc hi/lo split (row-major [b][s][h]) + encT hi ([b][h][s]) for context GEMM
__global__ void k_build_enc(const float* __restrict__ enc, f16* __restrict__ ehi,
                            f16* __restrict__ elo, f16* __restrict__ encT) {
    long n = (long)B_ * S_ * H_;
    for (long i = (long)blockIdx.x * 256 + threadIdx.x; i < n; i += (long)gridDim.x * 256) {
        float v = enc[i];
        f16 hi = (f16)v;
        ehi[i] = hi;
        elo[i] = (f16)(v - (float)hi);
        int h = (int)(i % H_);
        long bs = i / H_;
        int s = (int)(bs % S_), b = (int)(bs / S_);
        encT[((long)b * H_ + h) * S_ + s] = hi;
    }
}

// wPack[c8][g][kg][cl][ki] : c8 in [0,96), g in [0,3), kg in [0,192), cl in [0,8), ki in [0,4)
// value = w_hh[g*768 + c8*8+cl][kg*4+ki]
__global__ void k_build_wpack(const float* __restrict__ whh, float* __restrict__ wp) {
    long n = (long)H3 * H_;
    for (long i = (long)blockIdx.x * 256 + threadIdx.x; i < n; i += (long)gridDim.x * 256) {
        int ki = (int)(i & 3);
        long q = i >> 2;
        int cl = (int)(q & 7); q >>= 3;
        int kg = (int)(q % 192); q /= 192;
        int g = (int)(q % 3);
        int c8 = (int)(q / 3);
        int c = c8 * 8 + cl, k = kg * 4 + ki;
        wp[i] = whh[(long)(g * H_ + c) * H_ + k];
    }
}

__global__ void k_init_h(const float* __restrict__ hidden, float* __restrict__ hbuf) {
    int i = blockIdx.x * 256 + threadIdx.x;
    if (i < B_ * H_) hbuf[i] = hidden[i];
}

// ---------------------------------------------------------------- f16 MFMA GEMM
// C[M,N] = A[M,K] @ B[N,K]^T ; MODE 0: store, 1: store + bias[col], 2: C += result
template <int MODE>
__global__ __launch_bounds__(256) void k_gemm(const f16* __restrict__ A, const f16* __restrict__ Bm,
                                              float* __restrict__ C, const float* __restrict__ bias,
                                              int M, int N, int K, long sA, long sB, long sC) {
    A += (long)blockIdx.z * sA;
    Bm += (long)blockIdx.z * sB;
    C += (long)blockIdx.z * sC;
    const int m0 = blockIdx.y * 128, n0 = blockIdx.x * 128;
    __shared__ f16 As[128][56];   // stride 56 f16 = 112B: 16B-aligned, bank-spread
    __shared__ f16 Bs[128][56];
    const int tid = threadIdx.x, lane = tid & 63, wave = tid >> 6;
    const int wm = wave >> 1, wn = wave & 1;
    const int fr = lane & 15, kg = lane >> 4;
    f32x4 acc[4][4] = {};
    const int srow = tid >> 2, scol = (tid & 3) * 8;
    for (int kt = 0; kt < K; kt += 32) {
#pragma unroll
        for (int hh = 0; hh < 2; ++hh) {
            int r = srow + hh * 64;
            f16x8 va = {};
            int gr = m0 + r;
            if (gr < M) va = *(const f16x8*)(A + (long)gr * K + kt + scol);
            *(f16x8*)(&As[r][scol]) = va;
            f16x8 vb = {};
            int gc = n0 + r;
            if (gc < N) vb = *(const f16x8*)(Bm + (long)gc * K + kt + scol);
            *(f16x8*)(&Bs[r][scol]) = vb;
        }
        __syncthreads();
        f16x8 af[4], bf[4];
#pragma unroll
        for (int m = 0; m < 4; ++m) af[m] = *(const f16x8*)(&As[wm * 64 + m * 16 + fr][kg * 8]);
#pragma unroll
        for (int n = 0; n < 4; ++n) bf[n] = *(const f16x8*)(&Bs[wn * 64 + n * 16 + fr][kg * 8]);
#pragma unroll
        for (int m = 0; m < 4; ++m)
#pragma unroll
            for (int n = 0; n < 4; ++n)
                acc[m][n] = __builtin_amdgcn_mfma_f32_16x16x32_f16(af[m], bf[n], acc[m][n], 0, 0, 0);
        __syncthreads();
    }
    const int crow = m0 + wm * 64 + (lane >> 4) * 4;
    const int ccol = n0 + wn * 64 + fr;
#pragma unroll
    for (int n = 0; n < 4; ++n) {
        int col = ccol + n * 16;
        if (col >= N) continue;
        float bv = (MODE == 1) ? bias[col] : 0.f;
#pragma unroll
        for (int m = 0; m < 4; ++m) {
#pragma unroll
            for (int q = 0; q < 4; ++q) {
                int row = crow + m * 16 + q;
                if (row < M) {
                    long idx = (long)row * N + col;
                    float v = acc[m][n][q] + bv;
                    if (MODE == 2) v += C[idx];
                    C[idx] = v;
                }
            }
        }
    }
}

// ---------------------------------------------------------------- GRU recurrence
// 96 persistent blocks; block owns 8 hidden units (all 8 batches, all 3 gates).
// h double-buffered in global (device-scope atomics); per-step arrival counters.
__global__ __launch_bounds__(256) void k_gru(const float* __restrict__ gi, const float* __restrict__ wp,
                                             const float* __restrict__ bhh, float* hbuf,
                                             f16* __restrict__ Hhi, f16* __restrict__ Hlo, int* cnt) {
    __shared__ float hs[8][772];          // stride 772: 16B-aligned, banks spread by b*4
    __shared__ float part[4][64][3];
    const int tid = threadIdx.x;
    const int cl = tid & 7, b = (tid >> 3) & 7, kq = tid >> 6;
    const int c8 = blockIdx.x;
    const float* wbase = wp + (long)c8 * 18432;   // [3][192][8][4] floats
    for (int i = tid; i < B_ * H_; i += 256)
        hs[i / H_][i % H_] = __hip_atomic_load(hbuf + i, __ATOMIC_RELAXED, __HIP_MEMORY_SCOPE_AGENT);
    __syncthreads();
    for (int s = 0; s < 270; ++s) {
        float* gnext = hbuf + ((s + 1) & 1) * (B_ * H_);
        float ar = 0.f, az = 0.f, an = 0.f;
        const int kg0 = kq * 48;
#pragma unroll 4
        for (int kgi = 0; kgi < 48; ++kgi) {
            int kgg = kg0 + kgi;
            f32x4 hv = *(const f32x4*)(&hs[b][kgg * 4]);
            f32x4 wr = *(const f32x4*)(wbase + ((0 * 192 + kgg) * 8 + cl) * 4);
            f32x4 wz = *(const f32x4*)(wbase + ((1 * 192 + kgg) * 8 + cl) * 4);
            f32x4 wn = *(const f32x4*)(wbase + ((2 * 192 + kgg) * 8 + cl) * 4);
            ar += hv.x * wr.x + hv.y * wr.y + hv.z * wr.z + hv.w * wr.w;
            az += hv.x * wz.x + hv.y * wz.y + hv.z * wz.z + hv.w * wz.w;
            an += hv.x * wn.x + hv.y * wn.y + hv.z * wn.z + hv.w * wn.w;
        }
        int oi = b * 8 + cl;
        part[kq][oi][0] = ar;
        part[kq][oi][1] = az;
        part[kq][oi][2] = an;
        __syncthreads();
        if (tid < 64) {
            int bb = tid >> 3, c = c8 * 8 + (tid & 7);
            float gr = part[0][tid][0] + part[1][tid][0] + part[2][tid][0] + part[3][tid][0] + bhh[c];
            float gz = part[0][tid][1] + part[1][tid][1] + part[2][tid][1] + part[3][tid][1] + bhh[H_ + c];
            float gn = part[0][tid][2] + part[1][tid][2] + part[2][tid][2] + part[3][tid][2] + bhh[2 * H_ + c];
            long row = (long)bb * 270 + s;
            float ir = gi[row * H3 + c];
            float iz = gi[row * H3 + H_ + c];
            float in2 = gi[row * H3 + 2 * H_ + c];
            float rg = 1.f / (1.f + expf(-(ir + gr)));
            float zg = 1.f / (1.f + expf(-(iz + gz)));
            float ng = tanhf(in2 + rg * gn);
            float hold = hs[bb][c];
            float hnew = (1.f - zg) * ng + zg * hold;
            __hip_atomic_store(gnext + bb * H_ + c, hnew, __ATOMIC_RELAXED, __HIP_MEMORY_SCOPE_AGENT);
            f16 hi = (f16)hnew;
            Hhi[row * H_ + c] = hi;
            Hlo[row * H_ + c] = (f16)(hnew - (float)hi);
        }
        __syncthreads();
        if (tid == 0) {
            __hip_atomic_fetch_add(cnt + s, 1, __ATOMIC_ACQ_REL, __HIP_MEMORY_SCOPE_AGENT);
            while (__hip_atomic_load(cnt + s, __ATOMIC_ACQUIRE, __HIP_MEMORY_SCOPE_AGENT) < NBLK)
                __builtin_amdgcn_s_sleep(1);
        }
        __syncthreads();
        if (s < 269) {
            for (int i = tid; i < B_ * H_; i += 256)
                hs[i / H_][i % H_] =
                    __hip_atomic_load(gnext + i, __ATOMIC_RELAXED, __HIP_MEMORY_SCOPE_AGENT);
            __syncthreads();
        }
    }
}

// ---------------------------------------------------------------- attention softmax
__global__ __launch_bounds__(256) void k_attn_softmax(const float* __restrict__ lg,
                                                      const int* __restrict__ x, f16* __restrict__ ah) {
    __shared__ float red[256];
    int r = blockIdx.x, tid = threadIdx.x;
    int b = r / 270;
    const float* lr = lg + (long)r * S_;
    const int* xb = x + (long)b * S_;
    float v0 = lr[tid];
    if (xb[tid] == 0) v0 = -1e9f;
    float v1 = lr[tid + 256];
    if (xb[tid + 256] == 0) v1 = -1e9f;
    red[tid] = fmaxf(v0, v1);
    __syncthreads();
    for (int o = 128; o > 0; o >>= 1) {
        if (tid < o) red[tid] = fmaxf(red[tid], red[tid + o]);
        __syncthreads();
    }
    float m = red[0];
    __syncthreads();
    float e0 = __expf(v0 - m), e1 = __expf(v1 - m);
    red[tid] = e0 + e1;
    __syncthreads();
    for (int o = 128; o > 0; o >>= 1) {
        if (tid < o) red[tid] += red[tid + o];
        __syncthreads();
    }
    float inv = 1.f / red[0];
    ah[(long)r * S_ + tid] = (f16)(e0 * inv);
    ah[(long)r * S_ + tid + 256] = (f16)(e1 * inv);
}

// ---------------------------------------------------------------- p_gen
__global__ __launch_bounds__(256) void k_pgen(const f16* __restrict__ Wall, const f16* __restrict__ Hhi,
                                              const f16* __restrict__ Hlo, const float* __restrict__ ctx,
                                              const float* __restrict__ wg, const float* __restrict__ wgb,
                                              float* __restrict__ pg) {
    __shared__ float red[256];
    int r = blockIdx.x, tid = threadIdx.x;
    float a = 0.f;
    for (int i = tid; i < H_; i += 256) {
        a += (float)Wall[(long)r * H_ + i] * wg[i];
        a += ((float)Hhi[(long)r * H_ + i] + (float)Hlo[(long)r * H_ + i]) * wg[H_ + i];
        a += ctx[(long)r * H_ + i] * wg[2 * H_ + i];
    }
    red[tid] = a;
    __syncthreads();
    for (int o = 128; o > 0; o >>= 1) {
        if (tid < o) red[tid] += red[tid + o];
        __syncthreads();
    }
    if (tid == 0) pg[r] = 1.f / (1.f + expf(-(red[0] + wgb[0])));
}

// ---------------------------------------------------------------- vocab softmax stats (online)
__global__ __launch_bounds__(256) void k_rowstat(const float* __restrict__ out, float* __restrict__ rm,
                                                 float* __restrict__ rinv) {
    __shared__ float rm_s[256], rs_s[256];
    int r = blockIdx.x, tid = threadIdx.x;
    const f32x4* p = (const f32x4*)(out + (long)r * V_);
    float m = -3e38f, ssum = 0.f;
    for (int i = tid; i < V_ / 4; i += 256) {
        f32x4 v = p[i];
        float mv = fmaxf(fmaxf(v.x, v.y), fmaxf(v.z, v.w));
        if (mv > m) {
            ssum *= __expf(m - mv);
            m = mv;
        }
        ssum += __expf(v.x - m) + __expf(v.y - m) + __expf(v.z - m) + __expf(v.w - m);
    }
    rm_s[tid] = m;
    rs_s[tid] = ssum;
    __syncthreads();
    for (int o = 128; o > 0; o >>= 1) {
        if (tid < o) {
            float m2 = rm_s[tid + o], s2 = rs_s[tid + o];
            float M = fmaxf(rm_s[tid], m2);
            rs_s[tid] = rs_s[tid] * __expf(rm_s[tid] - M) + s2 * __expf(m2 - M);
            rm_s[tid] = M;
        }
        __syncthreads();
    }
    if (tid == 0) {
        rm[r] = rm_s[0];
        rinv[r] = 1.f / rs_s[0];
    }
}

// ---------------------------------------------------------------- finalize: p_gen * softmax (in place)
__global__ __launch_bounds__(256) void k_final(float* __restrict__ out, const float* __restrict__ rm,
                                               const float* __restrict__ rinv, const float* __restrict__ pg) {
    int r = blockIdx.y;
    int i = blockIdx.x * 256 + threadIdx.x;
    if (i >= V_ / 4) return;
    float m = rm[r], inv = rinv[r], p = pg[r];
    f32x4* po = (f32x4*)(out + (long)r * V_);
    f32x4 v = po[i];
    v.x = p * __expf(v.x - m) * inv;
    v.y = p * __expf(v.y - m) * inv;
    v.z = p * __expf(v.z - m) * inv;
    v.w = p * __expf(v.w - m) * inv;
    po[i] = v;
}

// ---------------------------------------------------------------- pointer scatter
__global__ __launch_bounds__(512) void k_scatter(float* __restrict__ out, const f16* __restrict__ ah,
                                                 const float* __restrict__ pg, const int* __restrict__ x) {
    int r = blockIdx.x, s = threadIdx.x;
    int b = r / 270;
    int xv = x[(long)b * S_ + s];
    if (xv == 0) return;
    float a = (float)ah[(long)r * S_ + s];
    if (a == 0.f) return;
    atomicAdd(out + (long)r * V_ + xv, (1.f - pg[r]) * a);
}

// ---------------------------------------------------------------- host
extern "C" void kernel_launch(void* const* d_in, const int* in_sizes, int n_in, void* d_out,
                              int out_size, void* d_ws, size_t ws_size, hipStream_t stream) {
    (void)in_sizes; (void)n_in; (void)out_size; (void)ws_size;
    const int* x = (const int*)d_in[0];
    const float* dec = (const float*)d_in[1];
    const float* enc = (const float*)d_in[2];
    const float* hid = (const float*)d_in[3];
    const int* tea = (const int*)d_in[4];
    const float* emb = (const float*)d_in[6];
    const float* wih = (const float*)d_in[7];
    const float* whh = (const float*)d_in[8];
    const float* bih = (const float*)d_in[9];
    const float* bhh = (const float*)d_in[10];
    const float* wgw = (const float*)d_in[11];
    const float* wgb = (const float*)d_in[12];
    float* out = (float*)d_out;

    char* w = (char*)d_ws;
    size_t off = 0;
    auto alloc = [&](size_t bytes) {
        void* p = w + off;
        off = (off + bytes + 255) & ~(size_t)255;
        return p;
    };
    int* cnt = (int*)alloc(270 * 4);
    float* hbuf = (float*)alloc(2 * B_ * H_ * 4);
    f16* Wall = (f16*)alloc((size_t)R_ * H_ * 2);
    f16* wih16 = (f16*)alloc((size_t)H3 * H_ * 2);
    float* giA = (float*)alloc((size_t)R_ * H3 * 4);
    float* wpk = (float*)alloc((size_t)H3 * H_ * 4);
    f16* Hhi = (f16*)alloc((size_t)R_ * H_ * 2);
    f16* Hlo = (f16*)alloc((size_t)R_ * H_ * 2);
    f16* emb16 = (f16*)alloc((size_t)V_ * H_ * 2);
    f16* ehi = (f16*)alloc((size_t)B_ * S_ * H_ * 2);
    f16* elo = (f16*)alloc((size_t)B_ * S_ * H_ * 2);
    f16* encT = (f16*)alloc((size_t)B_ * H_ * S_ * 2);
    float* lgH = (float*)alloc((size_t)R_ * S_ * 4);
    f16* ah = (f16*)alloc((size_t)R_ * S_ * 2);
    float* ctx = (float*)alloc((size_t)R_ * H_ * 4);
    float* pg = (float*)alloc(R_ * 4);
    float* rm = (float*)alloc(R_ * 4);
    float* rinv = (float*)alloc(R_ * 4);

    k_zero_cnt<<<1, 256, 0, stream>>>(cnt);
    k_cast<<<2048, 256, 0, stream>>>(emb, emb16, (long)V_ * H_);
    k_cast<<<512, 256, 0, stream>>>(wih, wih16, (long)H3 * H_);
    k_build_wall<<<R_, 256, 0, stream>>>(emb, dec, tea, Wall);
    k_build_enc<<<1024, 256, 0, stream>>>(enc, ehi, elo, encT);
    k_build_wpack<<<512, 256, 0, stream>>>(whh, wpk);
    k_init_h<<<24, 256, 0, stream>>>(hid, hbuf);

    // gi = W_all @ w_ih^T + b_ih
    {
        dim3 g(H3 / 128, (R_ + 127) / 128, 1);
        k_gemm<1><<<g, 256, 0, stream>>>(Wall, wih16, giA, bih, R_, H3, H_, 0, 0, 0);
    }
    k_gru<<<NBLK, 256, 0, stream>>>(giA, wpk, bhh, hbuf, Hhi, Hlo, cnt);

    // attention logits, hi/lo split: Hhi*Ehi + Hhi*Elo + Hlo*Ehi
    {
        dim3 g(S_ / 128, 3, 8);
        k_gemm<0><<<g, 256, 0, stream>>>(Hhi, ehi, lgH, nullptr, 270, S_, H_, 270L * H_, (long)S_ * H_, 270L * S_);
        k_gemm<2><<<g, 256, 0, stream>>>(Hhi, elo, lgH, nullptr, 270, S_, H_, 270L * H_, (long)S_ * H_, 270L * S_);
        k_gemm<2><<<g, 256, 0, stream>>>(Hlo, ehi, lgH, nullptr, 270, S_, H_, 270L * H_, (long)S_ * H_, 270L * S_);
    }
    k_attn_softmax<<<R_, 256, 0, stream>>>(lgH, x, ah);
    {
        dim3 g(H_ / 128, 3, 8);
        k_gemm<0><<<g, 256, 0, stream>>>(ah, encT, ctx, nullptr, 270, H_, S_, 270L * S_, (long)H_ * S_, 270L * H_);
    }
    k_pgen<<<R_, 256, 0, stream>>>(Wall, Hhi, Hlo, ctx, wgw, wgb, pg);

    // vocab logits straight into d_out
    {
        dim3 g((V_ + 127) / 128, (R_ + 127) / 128, 1);
        k_gemm<0><<<g, 256, 0, stream>>>(Hhi, emb16, out, nullptr, R_, V_, H_, 0, 0, 0);
    }
    k_rowstat<<<R_, 256, 0, stream>>>(out, rm, rinv);
    {
        dim3 g((V_ / 4 + 255) / 256, R_, 1);
        k_final<<<g, 256, 0, stream>>>(out, rm, rinv, pg);
    }
    k_scatter<<<R_, 512, 0, stream>>>(out, ah, pg, x);
}

// Round 2
// 4152.781 us; speedup vs baseline: 1.2555x; 1.2555x over previous
//
#include <hip/hip_runtime.h>
#include <hip/hip_bf16.h>

typedef _Float16 f16;
typedef _Float16 f16x8 __attribute__((ext_vector_type(8)));
typedef float f32x4 __attribute__((ext_vector_type(4)));

#define B_ 8
#define S_ 512
#define H_ 768
#define V_ 35004
#define J_ 30
#define K_ 9
#define R_ 2160          // B*J*K rows, row r = b*270 + j*9 + t  (matches out layout)
#define H3 2304
#define NBLK 96
#define NLEAF 12
#define LEAFSZ 8

// ---------------------------------------------------------------- prep kernels

__global__ void k_zero(int* p, int n) {
    int i = blockIdx.x * 256 + threadIdx.x;
    if (i < n) p[i] = 0;
}

__global__ void k_cast(const float* __restrict__ s, f16* __restrict__ d, long n) {
    for (long i = (long)blockIdx.x * 256 + threadIdx.x; i < n; i += (long)gridDim.x * 256)
        d[i] = (f16)s[i];
}

// W_all[r] = (t==0) ? decoder_input[b,j,:] : embed[teacher[b,j,t-1],:]
__global__ void k_build_wall(const float* __restrict__ emb, const float* __restrict__ dec,
                             const int* __restrict__ teacher, f16* __restrict__ Wall) {
    int r = blockIdx.x;
    int b = r / 270, s = r % 270, j = s / 9, t = s % 9;
    const float* src = (t == 0) ? dec + ((long)b * J_ + j) * H_
                                : emb + (long)teacher[((long)b * J_ + j) * K_ + (t - 1)] * H_;
    f16* dst = Wall + (long)r * H_;
    for (int c = threadIdx.x; c < H_; c += 256) dst[c] = (f16)src[c];
}

// enc hi/lo split (row-major [b][s][h]) + encT hi ([b][h][s]) for context GEMM
__global__ void k_build_enc(const float* __restrict__ enc, f16* __restrict__ ehi,
                            f16* __restrict__ elo, f16* __restrict__ encT) {
    long n = (long)B_ * S_ * H_;
    for (long i = (long)blockIdx.x * 256 + threadIdx.x; i < n; i += (long)gridDim.x * 256) {
        float v = enc[i];
        f16 hi = (f16)v;
        ehi[i] = hi;
        elo[i] = (f16)(v - (float)hi);
        int h = (int)(i % H_);
        long bs = i / H_;
        int s = (int)(bs % S_), b = (int)(bs / S_);
        encT[((long)b * H_ + h) * S_ + s] = hi;
    }
}

__global__ void k_init_h(const float* __restrict__ hidden, float* __restrict__ hbuf) {
    int i = blockIdx.x * 256 + threadIdx.x;
    if (i < B_ * H_) hbuf[i] = hidden[i];
}

// ---------------------------------------------------------------- f16 MFMA GEMM
// C[M,N] = A[M,K] @ B[N,K]^T ; MODE 0: store, 1: store + bias[col], 2: C += result
template <int MODE>
__global__ __launch_bounds__(256) void k_gemm(const f16* __restrict__ A, const f16* __restrict__ Bm,
                                              float* __restrict__ C, const float* __restrict__ bias,
                                              int M, int N, int K, long sA, long sB, long sC) {
    A += (long)blockIdx.z * sA;
    Bm += (long)blockIdx.z * sB;
    C += (long)blockIdx.z * sC;
    const int m0 = blockIdx.y * 128, n0 = blockIdx.x * 128;
    __shared__ f16 As[128][56];   // stride 56 f16 = 112B: 16B-aligned, bank-spread
    __shared__ f16 Bs[128][56];
    const int tid = threadIdx.x, lane = tid & 63, wave = tid >> 6;
    const int wm = wave >> 1, wn = wave & 1;
    const int fr = lane & 15, kg = lane >> 4;
    f32x4 acc[4][4] = {};
    const int srow = tid >> 2, scol = (tid & 3) * 8;
    for (int kt = 0; kt < K; kt += 32) {
#pragma unroll
        for (int hh = 0; hh < 2; ++hh) {
            int r = srow + hh * 64;
            f16x8 va = {};
            int gr = m0 + r;
            if (gr < M) va = *(const f16x8*)(A + (long)gr * K + kt + scol);
            *(f16x8*)(&As[r][scol]) = va;
            f16x8 vb = {};
            int gc = n0 + r;
            if (gc < N) vb = *(const f16x8*)(Bm + (long)gc * K + kt + scol);
            *(f16x8*)(&Bs[r][scol]) = vb;
        }
        __syncthreads();
        f16x8 af[4], bf[4];
#pragma unroll
        for (int m = 0; m < 4; ++m) af[m] = *(const f16x8*)(&As[wm * 64 + m * 16 + fr][kg * 8]);
#pragma unroll
        for (int n = 0; n < 4; ++n) bf[n] = *(const f16x8*)(&Bs[wn * 64 + n * 16 + fr][kg * 8]);
#pragma unroll
        for (int m = 0; m < 4; ++m)
#pragma unroll
            for (int n = 0; n < 4; ++n)
                acc[m][n] = __builtin_amdgcn_mfma_f32_16x16x32_f16(af[m], bf[n], acc[m][n], 0, 0, 0);
        __syncthreads();
    }
    const int crow = m0 + wm * 64 + (lane >> 4) * 4;
    const int ccol = n0 + wn * 64 + fr;
#pragma unroll
    for (int n = 0; n < 4; ++n) {
        int col = ccol + n * 16;
        if (col >= N) continue;
        float bv = (MODE == 1) ? bias[col] : 0.f;
#pragma unroll
        for (int m = 0; m < 4; ++m) {
#pragma unroll
            for (int q = 0; q < 4; ++q) {
                int row = crow + m * 16 + q;
                if (row < M) {
                    long idx = (long)row * N + col;
                    float v = acc[m][n][q] + bv;
                    if (MODE == 2) v += C[idx];
                    C[idx] = v;
                }
            }
        }
    }
}

// ---------------------------------------------------------------- GRU recurrence
// 96 persistent blocks; block owns 8 hidden units (all 8 batches, all 3 gates).
// Weight slice LDS-resident (loaded once from whh). All cross-block traffic via
// RELAXED cache-bypassing agent atomics; two-level arrival tree per step.
__global__ __launch_bounds__(256) void k_gru(const float* __restrict__ gi,
                                             const float* __restrict__ whh,
                                             const float* __restrict__ bhh, float* hbuf,
                                             f16* __restrict__ Hhi, f16* __restrict__ Hlo,
                                             int* leaf, int* root) {
    __shared__ f32x4 wsv[4608];           // [g][kg][cl] : ((g*192+kg)*8+cl), 73.7KB
    __shared__ float hs[8][772];          // stride 772: 16B-aligned, banks spread by b*4
    __shared__ float part[4][64][3];
    const int tid = threadIdx.x;
    const int cl = tid & 7, b = (tid >> 3) & 7, kq = tid >> 6;
    const int c8 = blockIdx.x;
    // pack weight slice into LDS: wsv[(g*192+kg)*8+cl] = whh[g*768 + c8*8+cl][kg*4 .. +3]
    for (int idx = tid; idx < 4608; idx += 256) {
        int cl2 = idx & 7, kg2 = (idx >> 3) % 192, g2 = idx / 1536;
        wsv[idx] = *(const f32x4*)(whh + (long)(g2 * H_ + c8 * 8 + cl2) * H_ + kg2 * 4);
    }
    float b_r = 0.f, b_z = 0.f, b_n = 0.f;
    if (tid < 64) {
        int c = c8 * 8 + (tid & 7);
        b_r = bhh[c];
        b_z = bhh[H_ + c];
        b_n = bhh[2 * H_ + c];
    }
    for (int i = tid; i < B_ * H_ / 2; i += 256) {
        unsigned long long v = __hip_atomic_load((const unsigned long long*)hbuf + i,
                                                 __ATOMIC_RELAXED, __HIP_MEMORY_SCOPE_AGENT);
        int f0 = i * 2;
        float* hp = &hs[0][0] + (f0 / H_) * 772 + (f0 % H_);
        hp[0] = __uint_as_float((unsigned)v);
        hp[1] = __uint_as_float((unsigned)(v >> 32));
    }
    __syncthreads();
    for (int s = 0; s < 270; ++s) {
        float* gnext = hbuf + ((s + 1) & 1) * (B_ * H_);
        float ar = 0.f, az = 0.f, an = 0.f;
        const int kg0 = kq * 48;
#pragma unroll 4
        for (int kgi = 0; kgi < 48; ++kgi) {
            int kgg = kg0 + kgi;
            f32x4 hv = *(const f32x4*)(&hs[b][kgg * 4]);
            f32x4 wr = wsv[kgg * 8 + cl];
            f32x4 wz = wsv[1536 + kgg * 8 + cl];
            f32x4 wn = wsv[3072 + kgg * 8 + cl];
            ar += hv.x * wr.x + hv.y * wr.y + hv.z * wr.z + hv.w * wr.w;
            az += hv.x * wz.x + hv.y * wz.y + hv.z * wz.z + hv.w * wz.w;
            an += hv.x * wn.x + hv.y * wn.y + hv.z * wn.z + hv.w * wn.w;
        }
        int oi = b * 8 + cl;
        part[kq][oi][0] = ar;
        part[kq][oi][1] = az;
        part[kq][oi][2] = an;
        __syncthreads();
        if (tid < 64) {
            int bb = tid >> 3, cc = tid & 7;
            int c = c8 * 8 + cc;
            float gr = part[0][tid][0] + part[1][tid][0] + part[2][tid][0] + part[3][tid][0] + b_r;
            float gz = part[0][tid][1] + part[1][tid][1] + part[2][tid][1] + part[3][tid][1] + b_z;
            float gn = part[0][tid][2] + part[1][tid][2] + part[2][tid][2] + part[3][tid][2] + b_n;
            long row = (long)bb * 270 + s;
            const float* gp = gi + row * H3;
            float rg = 1.f / (1.f + expf(-(gp[c] + gr)));
            float zg = 1.f / (1.f + expf(-(gp[H_ + c] + gz)));
            float ng = tanhf(gp[2 * H_ + c] + rg * gn);
            float hnew = (1.f - zg) * ng + zg * hs[bb][c];
            __hip_atomic_store(gnext + bb * H_ + c, hnew, __ATOMIC_RELAXED, __HIP_MEMORY_SCOPE_AGENT);
            f16 hi = (f16)hnew;
            Hhi[row * H_ + c] = hi;
            Hlo[row * H_ + c] = (f16)(hnew - (float)hi);
        }
        __syncthreads();   // compiler drains vmcnt(0) here -> h stores globally visible
        if (tid == 0) {
            int* lp = leaf + (s * NLEAF + (c8 >> 3)) * 32;
            int old = __hip_atomic_fetch_add(lp, 1, __ATOMIC_ACQ_REL, __HIP_MEMORY_SCOPE_AGENT);
            if (old == LEAFSZ - 1)
                __hip_atomic_fetch_add(root + s * 32, 1, __ATOMIC_RELEASE, __HIP_MEMORY_SCOPE_AGENT);
            while (__hip_atomic_load(root + s * 32, __ATOMIC_RELAXED, __HIP_MEMORY_SCOPE_AGENT) < NLEAF)
                __builtin_amdgcn_s_sleep(2);
        }
        __syncthreads();
        if (s < 269) {
            for (int i = tid; i < B_ * H_ / 2; i += 256) {
                unsigned long long v = __hip_atomic_load((const unsigned long long*)gnext + i,
                                                         __ATOMIC_RELAXED, __HIP_MEMORY_SCOPE_AGENT);
                int f0 = i * 2;
                float* hp = &hs[0][0] + (f0 / H_) * 772 + (f0 % H_);
                hp[0] = __uint_as_float((unsigned)v);
                hp[1] = __uint_as_float((unsigned)(v >> 32));
            }
            __syncthreads();
        }
    }
}

// ---------------------------------------------------------------- attention softmax
__global__ __launch_bounds__(256) void k_attn_softmax(const float* __restrict__ lg,
                                                      const int* __restrict__ x, f16* __restrict__ ah) {
    __shared__ float red[256];
    int r = blockIdx.x, tid = threadIdx.x;
    int b = r / 270;
    const float* lr = lg + (long)r * S_;
    const int* xb = x + (long)b * S_;
    float v0 = lr[tid];
    if (xb[tid] == 0) v0 = -1e9f;
    float v1 = lr[tid + 256];
    if (xb[tid + 256] == 0) v1 = -1e9f;
    red[tid] = fmaxf(v0, v1);
    __syncthreads();
    for (int o = 128; o > 0; o >>= 1) {
        if (tid < o) red[tid] = fmaxf(red[tid], red[tid + o]);
        __syncthreads();
    }
    float m = red[0];
    __syncthreads();
    float e0 = __expf(v0 - m), e1 = __expf(v1 - m);
    red[tid] = e0 + e1;
    __syncthreads();
    for (int o = 128; o > 0; o >>= 1) {
        if (tid < o) red[tid] += red[tid + o];
        __syncthreads();
    }
    float inv = 1.f / red[0];
    ah[(long)r * S_ + tid] = (f16)(e0 * inv);
    ah[(long)r * S_ + tid + 256] = (f16)(e1 * inv);
}

// ---------------------------------------------------------------- p_gen
__global__ __launch_bounds__(256) void k_pgen(const f16* __restrict__ Wall, const f16* __restrict__ Hhi,
                                              const f16* __restrict__ Hlo, const float* __restrict__ ctx,
                                              const float* __restrict__ wg, const float* __restrict__ wgb,
                                              float* __restrict__ pg) {
    __shared__ float red[256];
    int r = blockIdx.x, tid = threadIdx.x;
    float a = 0.f;
    for (int i = tid; i < H_; i += 256) {
        a += (float)Wall[(long)r * H_ + i] * wg[i];
        a += ((float)Hhi[(long)r * H_ + i] + (float)Hlo[(long)r * H_ + i]) * wg[H_ + i];
        a += ctx[(long)r * H_ + i] * wg[2 * H_ + i];
    }
    red[tid] = a;
    __syncthreads();
    for (int o = 128; o > 0; o >>= 1) {
        if (tid < o) red[tid] += red[tid + o];
        __syncthreads();
    }
    if (tid == 0) pg[r] = 1.f / (1.f + expf(-(red[0] + wgb[0])));
}

// ---------------------------------------------------------------- vocab softmax stats (online)
__global__ __launch_bounds__(256) void k_rowstat(const float* __restrict__ out, float* __restrict__ rm,
                                                 float* __restrict__ rinv) {
    __shared__ float rm_s[256], rs_s[256];
    int r = blockIdx.x, tid = threadIdx.x;
    const f32x4* p = (const f32x4*)(out + (long)r * V_);
    float m = -3e38f, ssum = 0.f;
    for (int i = tid; i < V_ / 4; i += 256) {
        f32x4 v = p[i];
        float mv = fmaxf(fmaxf(v.x, v.y), fmaxf(v.z, v.w));
        if (mv > m) {
            ssum *= __expf(m - mv);
            m = mv;
        }
        ssum += __expf(v.x - m) + __expf(v.y - m) + __expf(v.z - m) + __expf(v.w - m);
    }
    rm_s[tid] = m;
    rs_s[tid] = ssum;
    __syncthreads();
    for (int o = 128; o > 0; o >>= 1) {
        if (tid < o) {
            float m2 = rm_s[tid + o], s2 = rs_s[tid + o];
            float M = fmaxf(rm_s[tid], m2);
            rs_s[tid] = rs_s[tid] * __expf(rm_s[tid] - M) + s2 * __expf(m2 - M);
            rm_s[tid] = M;
        }
        __syncthreads();
    }
    if (tid == 0) {
        rm[r] = rm_s[0];
        rinv[r] = 1.f / rs_s[0];
    }
}

// ---------------------------------------------------------------- finalize: p_gen * softmax (in place)
__global__ __launch_bounds__(256) void k_final(float* __restrict__ out, const float* __restrict__ rm,
                                               const float* __restrict__ rinv, const float* __restrict__ pg) {
    int r = blockIdx.y;
    int i = blockIdx.x * 256 + threadIdx.x;
    if (i >= V_ / 4) return;
    float m = rm[r], inv = rinv[r], p = pg[r];
    f32x4* po = (f32x4*)(out + (long)r * V_);
    f32x4 v = po[i];
    v.x = p * __expf(v.x - m) * inv;
    v.y = p * __expf(v.y - m) * inv;
    v.z = p * __expf(v.z - m) * inv;
    v.w = p * __expf(v.w - m) * inv;
    po[i] = v;
}

// ---------------------------------------------------------------- pointer scatter
__global__ __launch_bounds__(512) void k_scatter(float* __restrict__ out, const f16* __restrict__ ah,
                                                 const float* __restrict__ pg, const int* __restrict__ x) {
    int r = blockIdx.x, s = threadIdx.x;
    int b = r / 270;
    int xv = x[(long)b * S_ + s];
    if (xv == 0) return;
    float a = (float)ah[(long)r * S_ + s];
    if (a == 0.f) return;
    atomicAdd(out + (long)r * V_ + xv, (1.f - pg[r]) * a);
}

// ---------------------------------------------------------------- host
extern "C" void kernel_launch(void* const* d_in, const int* in_sizes, int n_in, void* d_out,
                              int out_size, void* d_ws, size_t ws_size, hipStream_t stream) {
    (void)in_sizes; (void)n_in; (void)out_size; (void)ws_size;
    const int* x = (const int*)d_in[0];
    const float* dec = (const float*)d_in[1];
    const float* enc = (const float*)d_in[2];
    const float* hid = (const float*)d_in[3];
    const int* tea = (const int*)d_in[4];
    const float* emb = (const float*)d_in[6];
    const float* wih = (const float*)d_in[7];
    const float* whh = (const float*)d_in[8];
    const float* bih = (const float*)d_in[9];
    const float* bhh = (const float*)d_in[10];
    const float* wgw = (const float*)d_in[11];
    const float* wgb = (const float*)d_in[12];
    float* out = (float*)d_out;

    char* w = (char*)d_ws;
    size_t off = 0;
    auto alloc = [&](size_t bytes) {
        void* p = w + off;
        off = (off + bytes + 255) & ~(size_t)255;
        return p;
    };
    int* root = (int*)alloc(270 * 32 * 4);          // padded root counters
    int* leaf = (int*)alloc(270 * NLEAF * 32 * 4);  // padded leaf counters (contiguous after root)
    float* hbuf = (float*)alloc(2 * B_ * H_ * 4);
    f16* Wall = (f16*)alloc((size_t)R_ * H_ * 2);
    f16* wih16 = (f16*)alloc((size_t)H3 * H_ * 2);
    float* giA = (float*)alloc((size_t)R_ * H3 * 4);
    f16* Hhi = (f16*)alloc((size_t)R_ * H_ * 2);
    f16* Hlo = (f16*)alloc((size_t)R_ * H_ * 2);
    f16* emb16 = (f16*)alloc((size_t)V_ * H_ * 2);
    f16* ehi = (f16*)alloc((size_t)B_ * S_ * H_ * 2);
    f16* elo = (f16*)alloc((size_t)B_ * S_ * H_ * 2);
    f16* encT = (f16*)alloc((size_t)B_ * H_ * S_ * 2);
    float* lgH = (float*)alloc((size_t)R_ * S_ * 4);
    f16* ah = (f16*)alloc((size_t)R_ * S_ * 2);
    float* ctx = (float*)alloc((size_t)R_ * H_ * 4);
    float* pg = (float*)alloc(R_ * 4);
    float* rm = (float*)alloc(R_ * 4);
    float* rinv = (float*)alloc(R_ * 4);

    const int nCnt = 270 * 32 + 270 * NLEAF * 32;   // root + leaf ints (contiguous)
    k_zero<<<(nCnt + 255) / 256, 256, 0, stream>>>(root, nCnt);
    k_cast<<<2048, 256, 0, stream>>>(emb, emb16, (long)V_ * H_);
    k_cast<<<512, 256, 0, stream>>>(wih, wih16, (long)H3 * H_);
    k_build_wall<<<R_, 256, 0, stream>>>(emb, dec, tea, Wall);
    k_build_enc<<<1024, 256, 0, stream>>>(enc, ehi, elo, encT);
    k_init_h<<<24, 256, 0, stream>>>(hid, hbuf);

    // gi = W_all @ w_ih^T + b_ih
    {
        dim3 g(H3 / 128, (R_ + 127) / 128, 1);
        k_gemm<1><<<g, 256, 0, stream>>>(Wall, wih16, giA, bih, R_, H3, H_, 0, 0, 0);
    }
    k_gru<<<NBLK, 256, 0, stream>>>(giA, whh, bhh, hbuf, Hhi, Hlo, leaf, root);

    // attention logits, hi/lo split: Hhi*Ehi + Hhi*Elo + Hlo*Ehi
    {
        dim3 g(S_ / 128, 3, 8);
        k_gemm<0><<<g, 256, 0, stream>>>(Hhi, ehi, lgH, nullptr, 270, S_, H_, 270L * H_, (long)S_ * H_, 270L * S_);
        k_gemm<2><<<g, 256, 0, stream>>>(Hhi, elo, lgH, nullptr, 270, S_, H_, 270L * H_, (long)S_ * H_, 270L * S_);
        k_gemm<2><<<g, 256, 0, stream>>>(Hlo, ehi, lgH, nullptr, 270, S_, H_, 270L * H_, (long)S_ * H_, 270L * S_);
    }
    k_attn_softmax<<<R_, 256, 0, stream>>>(lgH, x, ah);
    {
        dim3 g(H_ / 128, 3, 8);
        k_gemm<0><<<g, 256, 0, stream>>>(ah, encT, ctx, nullptr, 270, H_, S_, 270L * S_, (long)H_ * S_, 270L * H_);
    }
    k_pgen<<<R_, 256, 0, stream>>>(Wall, Hhi, Hlo, ctx, wgw, wgb, pg);

    // vocab logits straight into d_out
    {
        dim3 g((V_ + 127) / 128, (R_ + 127) / 128, 1);
        k_gemm<0><<<g, 256, 0, stream>>>(Hhi, emb16, out, nullptr, R_, V_, H_, 0, 0, 0);
    }
    k_rowstat<<<R_, 256, 0, stream>>>(out, rm, rinv);
    {
        dim3 g((V_ / 4 + 255) / 256, R_, 1);
        k_final<<<g, 256, 0, stream>>>(out, rm, rinv, pg);
    }
    k_scatter<<<R_, 512, 0, stream>>>(out, ah, pg, x);
}

// Round 3
// 3239.613 us; speedup vs baseline: 1.6094x; 1.2819x over previous
//
#include <hip/hip_runtime.h>
#include <hip/hip_bf16.h>

typedef _Float16 f16;
typedef _Float16 f16x8 __attribute__((ext_vector_type(8)));
typedef float f32x4 __attribute__((ext_vector_type(4)));

#define B_ 8
#define S_ 512
#define H_ 768
#define V_ 35004
#define J_ 30
#define K_ 9
#define R_ 2160          // B*J*K rows, row r = b*270 + j*9 + t  (matches out layout)
#define H3 2304
#define NBLK 96

// ---------------------------------------------------------------- prep kernels

__global__ void k_zero(int* p, int n) {
    int i = blockIdx.x * 256 + threadIdx.x;
    if (i < n) p[i] = 0;
}

__global__ void k_cast(const float* __restrict__ s, f16* __restrict__ d, long n) {
    for (long i = (long)blockIdx.x * 256 + threadIdx.x; i < n; i += (long)gridDim.x * 256)
        d[i] = (f16)s[i];
}

// W_all[r] = (t==0) ? decoder_input[b,j,:] : embed[teacher[b,j,t-1],:]
__global__ void k_build_wall(const float* __restrict__ emb, const float* __restrict__ dec,
                             const int* __restrict__ teacher, f16* __restrict__ Wall) {
    int r = blockIdx.x;
    int b = r / 270, s = r % 270, j = s / 9, t = s % 9;
    const float* src = (t == 0) ? dec + ((long)b * J_ + j) * H_
                                : emb + (long)teacher[((long)b * J_ + j) * K_ + (t - 1)] * H_;
    f16* dst = Wall + (long)r * H_;
    for (int c = threadIdx.x; c < H_; c += 256) dst[c] = (f16)src[c];
}

// enc hi/lo split (row-major [b][s][h]) + encT hi ([b][h][s]) for context GEMM
__global__ void k_build_enc(const float* __restrict__ enc, f16* __restrict__ ehi,
                            f16* __restrict__ elo, f16* __restrict__ encT) {
    long n = (long)B_ * S_ * H_;
    for (long i = (long)blockIdx.x * 256 + threadIdx.x; i < n; i += (long)gridDim.x * 256) {
        float v = enc[i];
        f16 hi = (f16)v;
        ehi[i] = hi;
        elo[i] = (f16)(v - (float)hi);
        int h = (int)(i % H_);
        long bs = i / H_;
        int s = (int)(bs % S_), b = (int)(bs / S_);
        encT[((long)b * H_ + h) * S_ + s] = hi;
    }
}

__global__ void k_init_h(const float* __restrict__ hidden, float* __restrict__ hbuf) {
    int i = blockIdx.x * 256 + threadIdx.x;
    if (i < B_ * H_) hbuf[i] = hidden[i];
}

// ---------------------------------------------------------------- f16 MFMA GEMM
// C[M,N] = A[M,K] @ B[N,K]^T ; MODE 0: store, 1: store + bias[col], 2: C += result
template <int MODE>
__global__ __launch_bounds__(256) void k_gemm(const f16* __restrict__ A, const f16* __restrict__ Bm,
                                              float* __restrict__ C, const float* __restrict__ bias,
                                              int M, int N, int K, long sA, long sB, long sC) {
    A += (long)blockIdx.z * sA;
    Bm += (long)blockIdx.z * sB;
    C += (long)blockIdx.z * sC;
    const int m0 = blockIdx.y * 128, n0 = blockIdx.x * 128;
    __shared__ f16 As[128][56];   // stride 56 f16 = 112B: 16B-aligned, bank-spread
    __shared__ f16 Bs[128][56];
    const int tid = threadIdx.x, lane = tid & 63, wave = tid >> 6;
    const int wm = wave >> 1, wn = wave & 1;
    const int fr = lane & 15, kg = lane >> 4;
    f32x4 acc[4][4] = {};
    const int srow = tid >> 2, scol = (tid & 3) * 8;
    for (int kt = 0; kt < K; kt += 32) {
#pragma unroll
        for (int hh = 0; hh < 2; ++hh) {
            int r = srow + hh * 64;
            f16x8 va = {};
            int gr = m0 + r;
            if (gr < M) va = *(const f16x8*)(A + (long)gr * K + kt + scol);
            *(f16x8*)(&As[r][scol]) = va;
            f16x8 vb = {};
            int gc = n0 + r;
            if (gc < N) vb = *(const f16x8*)(Bm + (long)gc * K + kt + scol);
            *(f16x8*)(&Bs[r][scol]) = vb;
        }
        __syncthreads();
        f16x8 af[4], bf[4];
#pragma unroll
        for (int m = 0; m < 4; ++m) af[m] = *(const f16x8*)(&As[wm * 64 + m * 16 + fr][kg * 8]);
#pragma unroll
        for (int n = 0; n < 4; ++n) bf[n] = *(const f16x8*)(&Bs[wn * 64 + n * 16 + fr][kg * 8]);
#pragma unroll
        for (int m = 0; m < 4; ++m)
#pragma unroll
            for (int n = 0; n < 4; ++n)
                acc[m][n] = __builtin_amdgcn_mfma_f32_16x16x32_f16(af[m], bf[n], acc[m][n], 0, 0, 0);
        __syncthreads();
    }
    const int crow = m0 + wm * 64 + (lane >> 4) * 4;
    const int ccol = n0 + wn * 64 + fr;
#pragma unroll
    for (int n = 0; n < 4; ++n) {
        int col = ccol + n * 16;
        if (col >= N) continue;
        float bv = (MODE == 1) ? bias[col] : 0.f;
#pragma unroll
        for (int m = 0; m < 4; ++m) {
#pragma unroll
            for (int q = 0; q < 4; ++q) {
                int row = crow + m * 16 + q;
                if (row < M) {
                    long idx = (long)row * N + col;
                    float v = acc[m][n][q] + bv;
                    if (MODE == 2) v += C[idx];
                    C[idx] = v;
                }
            }
        }
    }
}

// ---------------------------------------------------------------- GRU recurrence
// 96 persistent blocks; block owns 8 hidden units (all 8 batches, all 3 gates).
// Weight slice LDS-resident. ALL cross-block atomics RELAXED agent-scope (sc1:
// executed at the cross-XCD coherence point; atomicity forces that regardless of
// ordering, and __syncthreads' vmcnt(0) drain provides the ordering) -> zero
// buffer_inv / buffer_wbl2 cache-maintenance ops in the loop.
__global__ __launch_bounds__(256) void k_gru(const float* __restrict__ gi,
                                             const float* __restrict__ whh,
                                             const float* __restrict__ bhh, float* hbuf,
                                             f16* __restrict__ Hhi, f16* __restrict__ Hlo,
                                             int* cnt) {
    __shared__ f32x4 wsv[4608];           // [g][kg][cl] : ((g*192+kg)*8+cl), 73.7KB
    __shared__ float hs[8][772];          // stride 772: 16B-aligned, banks spread by b*4
    __shared__ float part[4][64][3];
    const int tid = threadIdx.x;
    const int cl = tid & 7, b = (tid >> 3) & 7, kq = tid >> 6;
    const int c8 = blockIdx.x;
    // pack weight slice into LDS: wsv[(g*192+kg)*8+cl] = whh[g*768 + c8*8+cl][kg*4 .. +3]
    for (int idx = tid; idx < 4608; idx += 256) {
        int cl2 = idx & 7, kg2 = (idx >> 3) % 192, g2 = idx / 1536;
        wsv[idx] = *(const f32x4*)(whh + (long)(g2 * H_ + c8 * 8 + cl2) * H_ + kg2 * 4);
    }
    float b_r = 0.f, b_z = 0.f, b_n = 0.f;
    if (tid < 64) {
        int c = c8 * 8 + (tid & 7);
        b_r = bhh[c];
        b_z = bhh[H_ + c];
        b_n = bhh[2 * H_ + c];
    }
    for (int i = tid; i < B_ * H_ / 2; i += 256) {
        unsigned long long v = __hip_atomic_load((const unsigned long long*)hbuf + i,
                                                 __ATOMIC_RELAXED, __HIP_MEMORY_SCOPE_AGENT);
        int f0 = i * 2;
        float* hp = &hs[0][0] + (f0 / H_) * 772 + (f0 % H_);
        hp[0] = __uint_as_float((unsigned)v);
        hp[1] = __uint_as_float((unsigned)(v >> 32));
    }
    __syncthreads();
    for (int s = 0; s < 270; ++s) {
        float* gnext = hbuf + ((s + 1) & 1) * (B_ * H_);
        // prefetch this step's gi slice so its latency hides under the FMA loop
        float g0 = 0.f, g1 = 0.f, g2 = 0.f;
        if (tid < 64) {
            int c = c8 * 8 + (tid & 7);
            long row = (long)(tid >> 3) * 270 + s;
            const float* gp = gi + row * H3;
            g0 = gp[c];
            g1 = gp[H_ + c];
            g2 = gp[2 * H_ + c];
        }
        float ar = 0.f, az = 0.f, an = 0.f;
        const int kg0 = kq * 48;
#pragma unroll 4
        for (int kgi = 0; kgi < 48; ++kgi) {
            int kgg = kg0 + kgi;
            f32x4 hv = *(const f32x4*)(&hs[b][kgg * 4]);
            f32x4 wr = wsv[kgg * 8 + cl];
            f32x4 wz = wsv[1536 + kgg * 8 + cl];
            f32x4 wn = wsv[3072 + kgg * 8 + cl];
            ar += hv.x * wr.x + hv.y * wr.y + hv.z * wr.z + hv.w * wr.w;
            az += hv.x * wz.x + hv.y * wz.y + hv.z * wz.z + hv.w * wz.w;
            an += hv.x * wn.x + hv.y * wn.y + hv.z * wn.z + hv.w * wn.w;
        }
        int oi = b * 8 + cl;
        part[kq][oi][0] = ar;
        part[kq][oi][1] = az;
        part[kq][oi][2] = an;
        __syncthreads();
        if (tid < 64) {
            int bb = tid >> 3, cc = tid & 7;
            int c = c8 * 8 + cc;
            float gr = part[0][tid][0] + part[1][tid][0] + part[2][tid][0] + part[3][tid][0] + b_r;
            float gz = part[0][tid][1] + part[1][tid][1] + part[2][tid][1] + part[3][tid][1] + b_z;
            float gn = part[0][tid][2] + part[1][tid][2] + part[2][tid][2] + part[3][tid][2] + b_n;
            long row = (long)bb * 270 + s;
            float rg = 1.f / (1.f + expf(-(g0 + gr)));
            float zg = 1.f / (1.f + expf(-(g1 + gz)));
            float ng = tanhf(g2 + rg * gn);
            float hnew = (1.f - zg) * ng + zg * hs[bb][c];
            __hip_atomic_store(gnext + bb * H_ + c, hnew, __ATOMIC_RELAXED, __HIP_MEMORY_SCOPE_AGENT);
            f16 hi = (f16)hnew;
            Hhi[row * H_ + c] = hi;
            Hlo[row * H_ + c] = (f16)(hnew - (float)hi);
        }
        __syncthreads();   // compiler drains vmcnt(0) here -> h stores at coherence point
        if (tid == 0) {
            int* cp = cnt + s * 32;
            __hip_atomic_fetch_add(cp, 1, __ATOMIC_RELAXED, __HIP_MEMORY_SCOPE_AGENT);
            while (__hip_atomic_load(cp, __ATOMIC_RELAXED, __HIP_MEMORY_SCOPE_AGENT) < NBLK)
                __builtin_amdgcn_s_sleep(1);
        }
        __syncthreads();
        if (s < 269) {
            for (int i = tid; i < B_ * H_ / 2; i += 256) {
                unsigned long long v = __hip_atomic_load((const unsigned long long*)gnext + i,
                                                         __ATOMIC_RELAXED, __HIP_MEMORY_SCOPE_AGENT);
                int f0 = i * 2;
                float* hp = &hs[0][0] + (f0 / H_) * 772 + (f0 % H_);
                hp[0] = __uint_as_float((unsigned)v);
                hp[1] = __uint_as_float((unsigned)(v >> 32));
            }
            __syncthreads();
        }
    }
}

// ---------------------------------------------------------------- attention softmax
__global__ __launch_bounds__(256) void k_attn_softmax(const float* __restrict__ lg,
                                                      const int* __restrict__ x, f16* __restrict__ ah) {
    __shared__ float red[256];
    int r = blockIdx.x, tid = threadIdx.x;
    int b = r / 270;
    const float* lr = lg + (long)r * S_;
    const int* xb = x + (long)b * S_;
    float v0 = lr[tid];
    if (xb[tid] == 0) v0 = -1e9f;
    float v1 = lr[tid + 256];
    if (xb[tid + 256] == 0) v1 = -1e9f;
    red[tid] = fmaxf(v0, v1);
    __syncthreads();
    for (int o = 128; o > 0; o >>= 1) {
        if (tid < o) red[tid] = fmaxf(red[tid], red[tid + o]);
        __syncthreads();
    }
    float m = red[0];
    __syncthreads();
    float e0 = __expf(v0 - m), e1 = __expf(v1 - m);
    red[tid] = e0 + e1;
    __syncthreads();
    for (int o = 128; o > 0; o >>= 1) {
        if (tid < o) red[tid] += red[tid + o];
        __syncthreads();
    }
    float inv = 1.f / red[0];
    ah[(long)r * S_ + tid] = (f16)(e0 * inv);
    ah[(long)r * S_ + tid + 256] = (f16)(e1 * inv);
}

// ---------------------------------------------------------------- p_gen
__global__ __launch_bounds__(256) void k_pgen(const f16* __restrict__ Wall, const f16* __restrict__ Hhi,
                                              const f16* __restrict__ Hlo, const float* __restrict__ ctx,
                                              const float* __restrict__ wg, const float* __restrict__ wgb,
                                              float* __restrict__ pg) {
    __shared__ float red[256];
    int r = blockIdx.x, tid = threadIdx.x;
    float a = 0.f;
    for (int i = tid; i < H_; i += 256) {
        a += (float)Wall[(long)r * H_ + i] * wg[i];
        a += ((float)Hhi[(long)r * H_ + i] + (float)Hlo[(long)r * H_ + i]) * wg[H_ + i];
        a += ctx[(long)r * H_ + i] * wg[2 * H_ + i];
    }
    red[tid] = a;
    __syncthreads();
    for (int o = 128; o > 0; o >>= 1) {
        if (tid < o) red[tid] += red[tid + o];
        __syncthreads();
    }
    if (tid == 0) pg[r] = 1.f / (1.f + expf(-(red[0] + wgb[0])));
}

// ---------------------------------------------------------------- vocab softmax stats (online)
__global__ __launch_bounds__(256) void k_rowstat(const float* __restrict__ out, float* __restrict__ rm,
                                                 float* __restrict__ rinv) {
    __shared__ float rm_s[256], rs_s[256];
    int r = blockIdx.x, tid = threadIdx.x;
    const f32x4* p = (const f32x4*)(out + (long)r * V_);
    float m = -3e38f, ssum = 0.f;
    for (int i = tid; i < V_ / 4; i += 256) {
        f32x4 v = p[i];
        float mv = fmaxf(fmaxf(v.x, v.y), fmaxf(v.z, v.w));
        if (mv > m) {
            ssum *= __expf(m - mv);
            m = mv;
        }
        ssum += __expf(v.x - m) + __expf(v.y - m) + __expf(v.z - m) + __expf(v.w - m);
    }
    rm_s[tid] = m;
    rs_s[tid] = ssum;
    __syncthreads();
    for (int o = 128; o > 0; o >>= 1) {
        if (tid < o) {
            float m2 = rm_s[tid + o], s2 = rs_s[tid + o];
            float M = fmaxf(rm_s[tid], m2);
            rs_s[tid] = rs_s[tid] * __expf(rm_s[tid] - M) + s2 * __expf(m2 - M);
            rm_s[tid] = M;
        }
        __syncthreads();
    }
    if (tid == 0) {
        rm[r] = rm_s[0];
        rinv[r] = 1.f / rs_s[0];
    }
}

// ---------------------------------------------------------------- finalize: p_gen * softmax (in place)
__global__ __launch_bounds__(256) void k_final(float* __restrict__ out, const float* __restrict__ rm,
                                               const float* __restrict__ rinv, const float* __restrict__ pg) {
    int r = blockIdx.y;
    int i = blockIdx.x * 256 + threadIdx.x;
    if (i >= V_ / 4) return;
    float m = rm[r], inv = rinv[r], p = pg[r];
    f32x4* po = (f32x4*)(out + (long)r * V_);
    f32x4 v = po[i];
    v.x = p * __expf(v.x - m) * inv;
    v.y = p * __expf(v.y - m) * inv;
    v.z = p * __expf(v.z - m) * inv;
    v.w = p * __expf(v.w - m) * inv;
    po[i] = v;
}

// ---------------------------------------------------------------- pointer scatter
__global__ __launch_bounds__(512) void k_scatter(float* __restrict__ out, const f16* __restrict__ ah,
                                                 const float* __restrict__ pg, const int* __restrict__ x) {
    int r = blockIdx.x, s = threadIdx.x;
    int b = r / 270;
    int xv = x[(long)b * S_ + s];
    if (xv == 0) return;
    float a = (float)ah[(long)r * S_ + s];
    if (a == 0.f) return;
    atomicAdd(out + (long)r * V_ + xv, (1.f - pg[r]) * a);
}

// ---------------------------------------------------------------- host
extern "C" void kernel_launch(void* const* d_in, const int* in_sizes, int n_in, void* d_out,
                              int out_size, void* d_ws, size_t ws_size, hipStream_t stream) {
    (void)in_sizes; (void)n_in; (void)out_size; (void)ws_size;
    const int* x = (const int*)d_in[0];
    const float* dec = (const float*)d_in[1];
    const float* enc = (const float*)d_in[2];
    const float* hid = (const float*)d_in[3];
    const int* tea = (const int*)d_in[4];
    const float* emb = (const float*)d_in[6];
    const float* wih = (const float*)d_in[7];
    const float* whh = (const float*)d_in[8];
    const float* bih = (const float*)d_in[9];
    const float* bhh = (const float*)d_in[10];
    const float* wgw = (const float*)d_in[11];
    const float* wgb = (const float*)d_in[12];
    float* out = (float*)d_out;

    char* w = (char*)d_ws;
    size_t off = 0;
    auto alloc = [&](size_t bytes) {
        void* p = w + off;
        off = (off + bytes + 255) & ~(size_t)255;
        return p;
    };
    int* cnt = (int*)alloc(270 * 32 * 4);           // one padded counter per step
    float* hbuf = (float*)alloc(2 * B_ * H_ * 4);
    f16* Wall = (f16*)alloc((size_t)R_ * H_ * 2);
    f16* wih16 = (f16*)alloc((size_t)H3 * H_ * 2);
    float* giA = (float*)alloc((size_t)R_ * H3 * 4);
    f16* Hhi = (f16*)alloc((size_t)R_ * H_ * 2);
    f16* Hlo = (f16*)alloc((size_t)R_ * H_ * 2);
    f16* emb16 = (f16*)alloc((size_t)V_ * H_ * 2);
    f16* ehi = (f16*)alloc((size_t)B_ * S_ * H_ * 2);
    f16* elo = (f16*)alloc((size_t)B_ * S_ * H_ * 2);
    f16* encT = (f16*)alloc((size_t)B_ * H_ * S_ * 2);
    float* lgH = (float*)alloc((size_t)R_ * S_ * 4);
    f16* ah = (f16*)alloc((size_t)R_ * S_ * 2);
    float* ctx = (float*)alloc((size_t)R_ * H_ * 4);
    float* pg = (float*)alloc(R_ * 4);
    float* rm = (float*)alloc(R_ * 4);
    float* rinv = (float*)alloc(R_ * 4);

    const int nCnt = 270 * 32;
    k_zero<<<(nCnt + 255) / 256, 256, 0, stream>>>(cnt, nCnt);
    k_cast<<<2048, 256, 0, stream>>>(emb, emb16, (long)V_ * H_);
    k_cast<<<512, 256, 0, stream>>>(wih, wih16, (long)H3 * H_);
    k_build_wall<<<R_, 256, 0, stream>>>(emb, dec, tea, Wall);
    k_build_enc<<<1024, 256, 0, stream>>>(enc, ehi, elo, encT);
    k_init_h<<<24, 256, 0, stream>>>(hid, hbuf);

    // gi = W_all @ w_ih^T + b_ih
    {
        dim3 g(H3 / 128, (R_ + 127) / 128, 1);
        k_gemm<1><<<g, 256, 0, stream>>>(Wall, wih16, giA, bih, R_, H3, H_, 0, 0, 0);
    }
    k_gru<<<NBLK, 256, 0, stream>>>(giA, whh, bhh, hbuf, Hhi, Hlo, cnt);

    // attention logits, hi/lo split: Hhi*Ehi + Hhi*Elo + Hlo*Ehi
    {
        dim3 g(S_ / 128, 3, 8);
        k_gemm<0><<<g, 256, 0, stream>>>(Hhi, ehi, lgH, nullptr, 270, S_, H_, 270L * H_, (long)S_ * H_, 270L * S_);
        k_gemm<2><<<g, 256, 0, stream>>>(Hhi, elo, lgH, nullptr, 270, S_, H_, 270L * H_, (long)S_ * H_, 270L * S_);
        k_gemm<2><<<g, 256, 0, stream>>>(Hlo, ehi, lgH, nullptr, 270, S_, H_, 270L * H_, (long)S_ * H_, 270L * S_);
    }
    k_attn_softmax<<<R_, 256, 0, stream>>>(lgH, x, ah);
    {
        dim3 g(H_ / 128, 3, 8);
        k_gemm<0><<<g, 256, 0, stream>>>(ah, encT, ctx, nullptr, 270, H_, S_, 270L * S_, (long)H_ * S_, 270L * H_);
    }
    k_pgen<<<R_, 256, 0, stream>>>(Wall, Hhi, Hlo, ctx, wgw, wgb, pg);

    // vocab logits straight into d_out
    {
        dim3 g((V_ + 127) / 128, (R_ + 127) / 128, 1);
        k_gemm<0><<<g, 256, 0, stream>>>(Hhi, emb16, out, nullptr, R_, V_, H_, 0, 0, 0);
    }
    k_rowstat<<<R_, 256, 0, stream>>>(out, rm, rinv);
    {
        dim3 g((V_ / 4 + 255) / 256, R_, 1);
        k_final<<<g, 256, 0, stream>>>(out, rm, rinv, pg);
    }
    k_scatter<<<R_, 512, 0, stream>>>(out, ah, pg, x);
}

// Round 4
// 2150.927 us; speedup vs baseline: 2.4240x; 1.5061x over previous
//
#include <hip/hip_runtime.h>
#include <hip/hip_bf16.h>

typedef _Float16 f16;
typedef _Float16 f16x8 __attribute__((ext_vector_type(8)));
typedef float f32x4 __attribute__((ext_vector_type(4)));
typedef unsigned long long ull;

#define B_ 8
#define S_ 512
#define H_ 768
#define V_ 35004
#define J_ 30
#define K_ 9
#define R_ 2160          // B*J*K rows, row r = b*270 + j*9 + t  (matches out layout)
#define H3 2304
#define NGRP 4           // batch-pair groups
#define GBLK 48          // blocks per group
#define UPB 16           // hidden units per block

// ---------------------------------------------------------------- prep kernels

__global__ void k_zero(int* p, int n) {
    int i = blockIdx.x * 256 + threadIdx.x;
    if (i < n) p[i] = 0;
}

__global__ void k_cast(const float* __restrict__ s, f16* __restrict__ d, long n) {
    for (long i = (long)blockIdx.x * 256 + threadIdx.x; i < n; i += (long)gridDim.x * 256)
        d[i] = (f16)s[i];
}

// W_all[r] = (t==0) ? decoder_input[b,j,:] : embed[teacher[b,j,t-1],:]
__global__ void k_build_wall(const float* __restrict__ emb, const float* __restrict__ dec,
                             const int* __restrict__ teacher, f16* __restrict__ Wall) {
    int r = blockIdx.x;
    int b = r / 270, s = r % 270, j = s / 9, t = s % 9;
    const float* src = (t == 0) ? dec + ((long)b * J_ + j) * H_
                                : emb + (long)teacher[((long)b * J_ + j) * K_ + (t - 1)] * H_;
    f16* dst = Wall + (long)r * H_;
    for (int c = threadIdx.x; c < H_; c += 256) dst[c] = (f16)src[c];
}

// enc hi/lo split (row-major [b][s][h]) + encT hi ([b][h][s]) for context GEMM
__global__ void k_build_enc(const float* __restrict__ enc, f16* __restrict__ ehi,
                            f16* __restrict__ elo, f16* __restrict__ encT) {
    long n = (long)B_ * S_ * H_;
    for (long i = (long)blockIdx.x * 256 + threadIdx.x; i < n; i += (long)gridDim.x * 256) {
        float v = enc[i];
        f16 hi = (f16)v;
        ehi[i] = hi;
        elo[i] = (f16)(v - (float)hi);
        int h = (int)(i % H_);
        long bs = i / H_;
        int s = (int)(bs % S_), b = (int)(bs / S_);
        encT[((long)b * H_ + h) * S_ + s] = hi;
    }
}

__global__ void k_init_h(const float* __restrict__ hidden, float* __restrict__ hbuf) {
    int i = blockIdx.x * 256 + threadIdx.x;
    if (i < B_ * H_) hbuf[i] = hidden[i];
}

// ---------------------------------------------------------------- f16 MFMA GEMM
// C[M,N] = A[M,K] @ B[N,K]^T ; MODE 0: store, 1: store + bias[col], 2: C += result
template <int MODE>
__global__ __launch_bounds__(256) void k_gemm(const f16* __restrict__ A, const f16* __restrict__ Bm,
                                              float* __restrict__ C, const float* __restrict__ bias,
                                              int M, int N, int K, long sA, long sB, long sC) {
    A += (long)blockIdx.z * sA;
    Bm += (long)blockIdx.z * sB;
    C += (long)blockIdx.z * sC;
    const int m0 = blockIdx.y * 128, n0 = blockIdx.x * 128;
    __shared__ f16 As[128][56];   // stride 56 f16 = 112B: 16B-aligned, bank-spread
    __shared__ f16 Bs[128][56];
    const int tid = threadIdx.x, lane = tid & 63, wave = tid >> 6;
    const int wm = wave >> 1, wn = wave & 1;
    const int fr = lane & 15, kg = lane >> 4;
    f32x4 acc[4][4] = {};
    const int srow = tid >> 2, scol = (tid & 3) * 8;
    for (int kt = 0; kt < K; kt += 32) {
#pragma unroll
        for (int hh = 0; hh < 2; ++hh) {
            int r = srow + hh * 64;
            f16x8 va = {};
            int gr = m0 + r;
            if (gr < M) va = *(const f16x8*)(A + (long)gr * K + kt + scol);
            *(f16x8*)(&As[r][scol]) = va;
            f16x8 vb = {};
            int gc = n0 + r;
            if (gc < N) vb = *(const f16x8*)(Bm + (long)gc * K + kt + scol);
            *(f16x8*)(&Bs[r][scol]) = vb;
        }
        __syncthreads();
        f16x8 af[4], bf[4];
#pragma unroll
        for (int m = 0; m < 4; ++m) af[m] = *(const f16x8*)(&As[wm * 64 + m * 16 + fr][kg * 8]);
#pragma unroll
        for (int n = 0; n < 4; ++n) bf[n] = *(const f16x8*)(&Bs[wn * 64 + n * 16 + fr][kg * 8]);
#pragma unroll
        for (int m = 0; m < 4; ++m)
#pragma unroll
            for (int n = 0; n < 4; ++n)
                acc[m][n] = __builtin_amdgcn_mfma_f32_16x16x32_f16(af[m], bf[n], acc[m][n], 0, 0, 0);
        __syncthreads();
    }
    const int crow = m0 + wm * 64 + (lane >> 4) * 4;
    const int ccol = n0 + wn * 64 + fr;
#pragma unroll
    for (int n = 0; n < 4; ++n) {
        int col = ccol + n * 16;
        if (col >= N) continue;
        float bv = (MODE == 1) ? bias[col] : 0.f;
#pragma unroll
        for (int m = 0; m < 4; ++m) {
#pragma unroll
            for (int q = 0; q < 4; ++q) {
                int row = crow + m * 16 + q;
                if (row < M) {
                    long idx = (long)row * N + col;
                    float v = acc[m][n][q] + bv;
                    if (MODE == 2) v += C[idx];
                    C[idx] = v;
                }
            }
        }
    }
}

// ---------------------------------------------------------------- GRU recurrence
// 192 blocks = 4 batch-pair groups x 48 blocks x 16 units. f32 weight slice in
// LDS (147KB). Batches independent -> groups decoupled; per-step sync domain is
// 48 blocks via per-block FLAGS (no same-address RMW chain). All cross-block
// traffic RELAXED agent-scope atomics (coherence point); ordering from the
// vmcnt(0) drain of __syncthreads before the flag store / after flag observe.
__global__ __launch_bounds__(256) void k_gru(const float* __restrict__ gi,
                                             const float* __restrict__ whh,
                                             const float* __restrict__ bhh, float* hbuf,
                                             f16* __restrict__ Hhi, f16* __restrict__ Hlo,
                                             int* flags) {
    __shared__ f32x4 wsv[3 * 192 * 16];   // [g][k4][u] : 147456 B
    __shared__ float hs[2][776];          // h for the 2 batches of the pair
    __shared__ float part[8][32][3];
    const int tid = threadIdx.x;
    const int bp = blockIdx.x / GBLK;     // batch-pair group 0..3
    const int blk = blockIdx.x % GBLK;
    const int u0 = blk * UPB;
    // weight slice: wsv[(g*192+k4)*16+u] = whh[(g*768 + u0+u)*768 + k4*4 ..+3]
    for (int idx = tid; idx < 3 * 192 * 16; idx += 256) {
        int u = idx & 15, k4 = (idx >> 4) % 192, g = idx / (192 * 16);
        wsv[idx] = *(const f32x4*)(whh + (long)(g * H_ + u0 + u) * H_ + k4 * 4);
    }
    float b_r = 0.f, b_z = 0.f, b_n = 0.f;
    if (tid < 32) {
        int c = u0 + (tid & 15);
        b_r = bhh[c];
        b_z = bhh[H_ + c];
        b_n = bhh[2 * H_ + c];
    }
    // initial h for this pair (2*768 floats = 768 ull)
    for (int i = tid; i < 768; i += 256) {
        ull v = __hip_atomic_load((const ull*)hbuf + bp * 768 + i,
                                  __ATOMIC_RELAXED, __HIP_MEMORY_SCOPE_AGENT);
        int f0 = i * 2;
        float* hp = &hs[0][0] + (f0 / H_) * 776 + (f0 % H_);
        hp[0] = __uint_as_float((unsigned)v);
        hp[1] = __uint_as_float((unsigned)(v >> 32));
    }
    __syncthreads();
    const int u = tid & 15, b2 = (tid >> 4) & 1, q = tid >> 5;
    for (int s = 0; s < 270; ++s) {
        float* gnext = hbuf + ((s + 1) & 1) * (B_ * H_);
        // prefetch this step's gi (finisher threads), hides under FMA loop
        float g0 = 0.f, g1 = 0.f, g2 = 0.f;
        if (tid < 32) {
            int c = u0 + (tid & 15);
            long row = (long)(bp * 2 + (tid >> 4)) * 270 + s;
            const float* gp = gi + row * H3;
            g0 = gp[c];
            g1 = gp[H_ + c];
            g2 = gp[2 * H_ + c];
        }
        float ar = 0.f, az = 0.f, an = 0.f;
        const float* hb = &hs[b2][0];
#pragma unroll 4
        for (int i = 0; i < 24; ++i) {
            int k4 = i * 8 + q;
            f32x4 hv = *(const f32x4*)(hb + k4 * 4);
            f32x4 wr = wsv[k4 * 16 + u];
            f32x4 wz = wsv[(192 + k4) * 16 + u];
            f32x4 wn = wsv[(384 + k4) * 16 + u];
            ar += hv.x * wr.x + hv.y * wr.y + hv.z * wr.z + hv.w * wr.w;
            az += hv.x * wz.x + hv.y * wz.y + hv.z * wz.z + hv.w * wz.w;
            an += hv.x * wn.x + hv.y * wn.y + hv.z * wn.z + hv.w * wn.w;
        }
        int oi = (b2 << 4) | u;
        part[q][oi][0] = ar;
        part[q][oi][1] = az;
        part[q][oi][2] = an;
        __syncthreads();
        if (tid < 32) {
            float gr = b_r, gz = b_z, gn = b_n;
#pragma unroll
            for (int qq = 0; qq < 8; ++qq) {
                gr += part[qq][tid][0];
                gz += part[qq][tid][1];
                gn += part[qq][tid][2];
            }
            int c = u0 + (tid & 15);
            int bb = bp * 2 + (tid >> 4);
            long row = (long)bb * 270 + s;
            float rg = 1.f / (1.f + expf(-(g0 + gr)));
            float zg = 1.f / (1.f + expf(-(g1 + gz)));
            float ng = tanhf(g2 + rg * gn);
            float hnew = (1.f - zg) * ng + zg * hs[tid >> 4][c];
            __hip_atomic_store(gnext + bb * H_ + c, hnew, __ATOMIC_RELAXED, __HIP_MEMORY_SCOPE_AGENT);
            f16 hi16 = (f16)hnew;
            Hhi[row * H_ + c] = hi16;
            Hlo[row * H_ + c] = (f16)(hnew - (float)hi16);
        }
        __syncthreads();   // drains vmcnt(0): h stores visible at coherence point
        if (tid == 0)
            __hip_atomic_store(flags + (s * NGRP + bp) * 64 + blk, 1,
                               __ATOMIC_RELAXED, __HIP_MEMORY_SCOPE_AGENT);
        if (tid < 64) {    // wave 0 polls its group's 48 flags (24 ull)
            const ull* fp = (const ull*)(flags + (s * NGRP + bp) * 64);
            bool ok;
            do {
                ok = true;
                if (tid < 24) {
                    ull v = __hip_atomic_load(fp + tid, __ATOMIC_RELAXED, __HIP_MEMORY_SCOPE_AGENT);
                    ok = (v == 0x0000000100000001ULL);
                }
            } while (!__all(ok));
        }
        __syncthreads();
        if (s < 269) {
            for (int i = tid; i < 768; i += 256) {
                ull v = __hip_atomic_load((const ull*)gnext + bp * 768 + i,
                                          __ATOMIC_RELAXED, __HIP_MEMORY_SCOPE_AGENT);
                int f0 = i * 2;
                float* hp = &hs[0][0] + (f0 / H_) * 776 + (f0 % H_);
                hp[0] = __uint_as_float((unsigned)v);
                hp[1] = __uint_as_float((unsigned)(v >> 32));
            }
            __syncthreads();
        }
    }
}

// ---------------------------------------------------------------- attention softmax
__global__ __launch_bounds__(256) void k_attn_softmax(const float* __restrict__ lg,
                                                      const int* __restrict__ x, f16* __restrict__ ah) {
    __shared__ float red[256];
    int r = blockIdx.x, tid = threadIdx.x;
    int b = r / 270;
    const float* lr = lg + (long)r * S_;
    const int* xb = x + (long)b * S_;
    float v0 = lr[tid];
    if (xb[tid] == 0) v0 = -1e9f;
    float v1 = lr[tid + 256];
    if (xb[tid + 256] == 0) v1 = -1e9f;
    red[tid] = fmaxf(v0, v1);
    __syncthreads();
    for (int o = 128; o > 0; o >>= 1) {
        if (tid < o) red[tid] = fmaxf(red[tid], red[tid + o]);
        __syncthreads();
    }
    float m = red[0];
    __syncthreads();
    float e0 = __expf(v0 - m), e1 = __expf(v1 - m);
    red[tid] = e0 + e1;
    __syncthreads();
    for (int o = 128; o > 0; o >>= 1) {
        if (tid < o) red[tid] += red[tid + o];
        __syncthreads();
    }
    float inv = 1.f / red[0];
    ah[(long)r * S_ + tid] = (f16)(e0 * inv);
    ah[(long)r * S_ + tid + 256] = (f16)(e1 * inv);
}

// ---------------------------------------------------------------- p_gen
__global__ __launch_bounds__(256) void k_pgen(const f16* __restrict__ Wall, const f16* __restrict__ Hhi,
                                              const f16* __restrict__ Hlo, const float* __restrict__ ctx,
                                              const float* __restrict__ wg, const float* __restrict__ wgb,
                                              float* __restrict__ pg) {
    __shared__ float red[256];
    int r = blockIdx.x, tid = threadIdx.x;
    float a = 0.f;
    for (int i = tid; i < H_; i += 256) {
        a += (float)Wall[(long)r * H_ + i] * wg[i];
        a += ((float)Hhi[(long)r * H_ + i] + (float)Hlo[(long)r * H_ + i]) * wg[H_ + i];
        a += ctx[(long)r * H_ + i] * wg[2 * H_ + i];
    }
    red[tid] = a;
    __syncthreads();
    for (int o = 128; o > 0; o >>= 1) {
        if (tid < o) red[tid] += red[tid + o];
        __syncthreads();
    }
    if (tid == 0) pg[r] = 1.f / (1.f + expf(-(red[0] + wgb[0])));
}

// ---------------------------------------------------------------- vocab softmax stats (online)
__global__ __launch_bounds__(256) void k_rowstat(const float* __restrict__ out, float* __restrict__ rm,
                                                 float* __restrict__ rinv) {
    __shared__ float rm_s[256], rs_s[256];
    int r = blockIdx.x, tid = threadIdx.x;
    const f32x4* p = (const f32x4*)(out + (long)r * V_);
    float m = -3e38f, ssum = 0.f;
    for (int i = tid; i < V_ / 4; i += 256) {
        f32x4 v = p[i];
        float mv = fmaxf(fmaxf(v.x, v.y), fmaxf(v.z, v.w));
        if (mv > m) {
            ssum *= __expf(m - mv);
            m = mv;
        }
        ssum += __expf(v.x - m) + __expf(v.y - m) + __expf(v.z - m) + __expf(v.w - m);
    }
    rm_s[tid] = m;
    rs_s[tid] = ssum;
    __syncthreads();
    for (int o = 128; o > 0; o >>= 1) {
        if (tid < o) {
            float m2 = rm_s[tid + o], s2 = rs_s[tid + o];
            float M = fmaxf(rm_s[tid], m2);
            rs_s[tid] = rs_s[tid] * __expf(rm_s[tid] - M) + s2 * __expf(m2 - M);
            rm_s[tid] = M;
        }
        __syncthreads();
    }
    if (tid == 0) {
        rm[r] = rm_s[0];
        rinv[r] = 1.f / rs_s[0];
    }
}

// ---------------------------------------------------------------- finalize: p_gen * softmax (in place)
__global__ __launch_bounds__(256) void k_final(float* __restrict__ out, const float* __restrict__ rm,
                                               const float* __restrict__ rinv, const float* __restrict__ pg) {
    int r = blockIdx.y;
    int i = blockIdx.x * 256 + threadIdx.x;
    if (i >= V_ / 4) return;
    float m = rm[r], inv = rinv[r], p = pg[r];
    f32x4* po = (f32x4*)(out + (long)r * V_);
    f32x4 v = po[i];
    v.x = p * __expf(v.x - m) * inv;
    v.y = p * __expf(v.y - m) * inv;
    v.z = p * __expf(v.z - m) * inv;
    v.w = p * __expf(v.w - m) * inv;
    po[i] = v;
}

// ---------------------------------------------------------------- pointer scatter
__global__ __launch_bounds__(512) void k_scatter(float* __restrict__ out, const f16* __restrict__ ah,
                                                 const float* __restrict__ pg, const int* __restrict__ x) {
    int r = blockIdx.x, s = threadIdx.x;
    int b = r / 270;
    int xv = x[(long)b * S_ + s];
    if (xv == 0) return;
    float a = (float)ah[(long)r * S_ + s];
    if (a == 0.f) return;
    atomicAdd(out + (long)r * V_ + xv, (1.f - pg[r]) * a);
}

// ---------------------------------------------------------------- host
extern "C" void kernel_launch(void* const* d_in, const int* in_sizes, int n_in, void* d_out,
                              int out_size, void* d_ws, size_t ws_size, hipStream_t stream) {
    (void)in_sizes; (void)n_in; (void)out_size; (void)ws_size;
    const int* x = (const int*)d_in[0];
    const float* dec = (const float*)d_in[1];
    const float* enc = (const float*)d_in[2];
    const float* hid = (const float*)d_in[3];
    const int* tea = (const int*)d_in[4];
    const float* emb = (const float*)d_in[6];
    const float* wih = (const float*)d_in[7];
    const float* whh = (const float*)d_in[8];
    const float* bih = (const float*)d_in[9];
    const float* bhh = (const float*)d_in[10];
    const float* wgw = (const float*)d_in[11];
    const float* wgb = (const float*)d_in[12];
    float* out = (float*)d_out;

    char* w = (char*)d_ws;
    size_t off = 0;
    auto alloc = [&](size_t bytes) {
        void* p = w + off;
        off = (off + bytes + 255) & ~(size_t)255;
        return p;
    };
    int* flags = (int*)alloc(270 * NGRP * 64 * 4);  // per-step per-group flag rows
    float* hbuf = (float*)alloc(2 * B_ * H_ * 4);
    f16* Wall = (f16*)alloc((size_t)R_ * H_ * 2);
    f16* wih16 = (f16*)alloc((size_t)H3 * H_ * 2);
    float* giA = (float*)alloc((size_t)R_ * H3 * 4);
    f16* Hhi = (f16*)alloc((size_t)R_ * H_ * 2);
    f16* Hlo = (f16*)alloc((size_t)R_ * H_ * 2);
    f16* emb16 = (f16*)alloc((size_t)V_ * H_ * 2);
    f16* ehi = (f16*)alloc((size_t)B_ * S_ * H_ * 2);
    f16* elo = (f16*)alloc((size_t)B_ * S_ * H_ * 2);
    f16* encT = (f16*)alloc((size_t)B_ * H_ * S_ * 2);
    float* lgH = (float*)alloc((size_t)R_ * S_ * 4);
    f16* ah = (f16*)alloc((size_t)R_ * S_ * 2);
    float* ctx = (float*)alloc((size_t)R_ * H_ * 4);
    float* pg = (float*)alloc(R_ * 4);
    float* rm = (float*)alloc(R_ * 4);
    float* rinv = (float*)alloc(R_ * 4);

    const int nCnt = 270 * NGRP * 64;
    k_zero<<<(nCnt + 255) / 256, 256, 0, stream>>>(flags, nCnt);
    k_cast<<<2048, 256, 0, stream>>>(emb, emb16, (long)V_ * H_);
    k_cast<<<512, 256, 0, stream>>>(wih, wih16, (long)H3 * H_);
    k_build_wall<<<R_, 256, 0, stream>>>(emb, dec, tea, Wall);
    k_build_enc<<<1024, 256, 0, stream>>>(enc, ehi, elo, encT);
    k_init_h<<<24, 256, 0, stream>>>(hid, hbuf);

    // gi = W_all @ w_ih^T + b_ih
    {
        dim3 g(H3 / 128, (R_ + 127) / 128, 1);
        k_gemm<1><<<g, 256, 0, stream>>>(Wall, wih16, giA, bih, R_, H3, H_, 0, 0, 0);
    }
    k_gru<<<NGRP * GBLK, 256, 0, stream>>>(giA, whh, bhh, hbuf, Hhi, Hlo, flags);

    // attention logits, hi/lo split: Hhi*Ehi + Hhi*Elo + Hlo*Ehi
    {
        dim3 g(S_ / 128, 3, 8);
        k_gemm<0><<<g, 256, 0, stream>>>(Hhi, ehi, lgH, nullptr, 270, S_, H_, 270L * H_, (long)S_ * H_, 270L * S_);
        k_gemm<2><<<g, 256, 0, stream>>>(Hhi, elo, lgH, nullptr, 270, S_, H_, 270L * H_, (long)S_ * H_, 270L * S_);
        k_gemm<2><<<g, 256, 0, stream>>>(Hlo, ehi, lgH, nullptr, 270, S_, H_, 270L * H_, (long)S_ * H_, 270L * S_);
    }
    k_attn_softmax<<<R_, 256, 0, stream>>>(lgH, x, ah);
    {
        dim3 g(H_ / 128, 3, 8);
        k_gemm<0><<<g, 256, 0, stream>>>(ah, encT, ctx, nullptr, 270, H_, S_, 270L * S_, (long)H_ * S_, 270L * H_);
    }
    k_pgen<<<R_, 256, 0, stream>>>(Wall, Hhi, Hlo, ctx, wgw, wgb, pg);

    // vocab logits straight into d_out
    {
        dim3 g((V_ + 127) / 128, (R_ + 127) / 128, 1);
        k_gemm<0><<<g, 256, 0, stream>>>(Hhi, emb16, out, nullptr, R_, V_, H_, 0, 0, 0);
    }
    k_rowstat<<<R_, 256, 0, stream>>>(out, rm, rinv);
    {
        dim3 g((V_ / 4 + 255) / 256, R_, 1);
        k_final<<<g, 256, 0, stream>>>(out, rm, rinv, pg);
    }
    k_scatter<<<R_, 512, 0, stream>>>(out, ah, pg, x);
}

// Round 5
// 1659.389 us; speedup vs baseline: 3.1420x; 1.2962x over previous
//
#include <hip/hip_runtime.h>
#include <hip/hip_bf16.h>

typedef _Float16 f16;
typedef _Float16 f16x8 __attribute__((ext_vector_type(8)));
typedef float f32x4 __attribute__((ext_vector_type(4)));
typedef unsigned long long ull;

#define B_ 8
#define S_ 512
#define H_ 768
#define V_ 35004
#define J_ 30
#define K_ 9
#define R_ 2160          // B*J*K rows, row r = b*270 + j*9 + t  (matches out layout)
#define H3 2304
#define NGRP 4           // batch-pair groups
#define GBLK 48          // blocks per group
#define UPB 16           // hidden units per block

// ---------------------------------------------------------------- prep kernels

__global__ void k_zero(int* p, int n) {
    int i = blockIdx.x * 256 + threadIdx.x;
    if (i < n) p[i] = 0;
}

__global__ void k_cast(const float* __restrict__ s, f16* __restrict__ d, long n) {
    for (long i = (long)blockIdx.x * 256 + threadIdx.x; i < n; i += (long)gridDim.x * 256)
        d[i] = (f16)s[i];
}

// W_all[r] = (t==0) ? decoder_input[b,j,:] : embed[teacher[b,j,t-1],:]
__global__ void k_build_wall(const float* __restrict__ emb, const float* __restrict__ dec,
                             const int* __restrict__ teacher, f16* __restrict__ Wall) {
    int r = blockIdx.x;
    int b = r / 270, s = r % 270, j = s / 9, t = s % 9;
    const float* src = (t == 0) ? dec + ((long)b * J_ + j) * H_
                                : emb + (long)teacher[((long)b * J_ + j) * K_ + (t - 1)] * H_;
    f16* dst = Wall + (long)r * H_;
    for (int c = threadIdx.x; c < H_; c += 256) dst[c] = (f16)src[c];
}

// enc hi/lo split (row-major [b][s][h]) + encT hi ([b][h][s]) for context GEMM
__global__ void k_build_enc(const float* __restrict__ enc, f16* __restrict__ ehi,
                            f16* __restrict__ elo, f16* __restrict__ encT) {
    long n = (long)B_ * S_ * H_;
    for (long i = (long)blockIdx.x * 256 + threadIdx.x; i < n; i += (long)gridDim.x * 256) {
        float v = enc[i];
        f16 hi = (f16)v;
        ehi[i] = hi;
        elo[i] = (f16)(v - (float)hi);
        int h = (int)(i % H_);
        long bs = i / H_;
        int s = (int)(bs % S_), b = (int)(bs / S_);
        encT[((long)b * H_ + h) * S_ + s] = hi;
    }
}

// h exchange word: {seq:32 | f32 bits:32}. Parity-0 region gets seq=0 initial h.
__global__ void k_init_h(const float* __restrict__ hidden, ull* __restrict__ hbuf) {
    int i = blockIdx.x * 256 + threadIdx.x;
    if (i < B_ * H_) {
        int b = i / H_, u = i % H_;
        unsigned bits = __float_as_uint(hidden[i]);
        hbuf[(long)(b >> 1) * 1536 + (b & 1) * 768 + u] = (ull)bits;  // seq 0
    }
}

// ---------------------------------------------------------------- f16 MFMA GEMM
// C[M,N] = A[M,K] @ B[N,K]^T ; MODE 0: store, 1: store + bias[col], 2: C += result
template <int MODE>
__global__ __launch_bounds__(256) void k_gemm(const f16* __restrict__ A, const f16* __restrict__ Bm,
                                              float* __restrict__ C, const float* __restrict__ bias,
                                              int M, int N, int K, long sA, long sB, long sC) {
    A += (long)blockIdx.z * sA;
    Bm += (long)blockIdx.z * sB;
    C += (long)blockIdx.z * sC;
    const int m0 = blockIdx.y * 128, n0 = blockIdx.x * 128;
    __shared__ f16 As[128][56];   // stride 56 f16 = 112B: 16B-aligned, bank-spread
    __shared__ f16 Bs[128][56];
    const int tid = threadIdx.x, lane = tid & 63, wave = tid >> 6;
    const int wm = wave >> 1, wn = wave & 1;
    const int fr = lane & 15, kg = lane >> 4;
    f32x4 acc[4][4] = {};
    const int srow = tid >> 2, scol = (tid & 3) * 8;
    for (int kt = 0; kt < K; kt += 32) {
#pragma unroll
        for (int hh = 0; hh < 2; ++hh) {
            int r = srow + hh * 64;
            f16x8 va = {};
            int gr = m0 + r;
            if (gr < M) va = *(const f16x8*)(A + (long)gr * K + kt + scol);
            *(f16x8*)(&As[r][scol]) = va;
            f16x8 vb = {};
            int gc = n0 + r;
            if (gc < N) vb = *(const f16x8*)(Bm + (long)gc * K + kt + scol);
            *(f16x8*)(&Bs[r][scol]) = vb;
        }
        __syncthreads();
        f16x8 af[4], bf[4];
#pragma unroll
        for (int m = 0; m < 4; ++m) af[m] = *(const f16x8*)(&As[wm * 64 + m * 16 + fr][kg * 8]);
#pragma unroll
        for (int n = 0; n < 4; ++n) bf[n] = *(const f16x8*)(&Bs[wn * 64 + n * 16 + fr][kg * 8]);
#pragma unroll
        for (int m = 0; m < 4; ++m)
#pragma unroll
            for (int n = 0; n < 4; ++n)
                acc[m][n] = __builtin_amdgcn_mfma_f32_16x16x32_f16(af[m], bf[n], acc[m][n], 0, 0, 0);
        __syncthreads();
    }
    const int crow = m0 + wm * 64 + (lane >> 4) * 4;
    const int ccol = n0 + wn * 64 + fr;
#pragma unroll
    for (int n = 0; n < 4; ++n) {
        int col = ccol + n * 16;
        if (col >= N) continue;
        float bv = (MODE == 1) ? bias[col] : 0.f;
#pragma unroll
        for (int m = 0; m < 4; ++m) {
#pragma unroll
            for (int q = 0; q < 4; ++q) {
                int row = crow + m * 16 + q;
                if (row < M) {
                    long idx = (long)row * N + col;
                    float v = acc[m][n][q] + bv;
                    if (MODE == 2) v += C[idx];
                    C[idx] = v;
                }
            }
        }
    }
}

// ---------------------------------------------------------------- GRU recurrence
// 192 blocks = 4 batch-pair groups x 48 blocks x 16 units; f32 weights in LDS.
// h exchange: each value is a ull {seq<<32 | f32} stored with ONE relaxed
// agent atomic; readers poll their 6 words for seq==s. Data dependency bounds
// block spread to 1 step -> parity double-buffer, no flags, no global barrier.
__global__ __launch_bounds__(256) void k_gru(const float* __restrict__ gi,
                                             const float* __restrict__ whh,
                                             const float* __restrict__ bhh,
                                             ull* hbuf,
                                             f16* __restrict__ Hhi, f16* __restrict__ Hlo) {
    __shared__ f32x4 wsv[3 * 192 * 16];   // [g][k4][u] : 147456 B
    __shared__ float hs[2][776];          // h for the 2 batches of the pair
    __shared__ float part[8][32][3];
    const int tid = threadIdx.x;
    const int bp = blockIdx.x / GBLK;     // batch-pair group 0..3
    const int blk = blockIdx.x % GBLK;
    const int u0 = blk * UPB;
    for (int idx = tid; idx < 3 * 192 * 16; idx += 256) {
        int uu = idx & 15, k4 = (idx >> 4) % 192, g = idx / (192 * 16);
        wsv[idx] = *(const f32x4*)(whh + (long)(g * H_ + u0 + uu) * H_ + k4 * 4);
    }
    float b_r = 0.f, b_z = 0.f, b_n = 0.f;
    if (tid < 32) {
        int c = u0 + (tid & 15);
        b_r = bhh[c];
        b_z = bhh[H_ + c];
        b_n = bhh[2 * H_ + c];
    }
    __syncthreads();
    const int u = tid & 15, b2 = (tid >> 4) & 1, q = tid >> 5;
    ull* base0 = hbuf + (long)bp * 1536;
    ull* base1 = hbuf + (long)NGRP * 1536 + (long)bp * 1536;
    for (int s = 0; s < 270; ++s) {
        ull* rbuf = (s & 1) ? base1 : base0;
        ull* wbuf = (s & 1) ? base0 : base1;
        // ---- poll + load h_s (6 words per thread), then stage into LDS
        const unsigned want = (unsigned)s;
        ull v0, v1, v2, v3, v4, v5;
        for (;;) {
            v0 = __hip_atomic_load(rbuf + tid, __ATOMIC_RELAXED, __HIP_MEMORY_SCOPE_AGENT);
            v1 = __hip_atomic_load(rbuf + tid + 256, __ATOMIC_RELAXED, __HIP_MEMORY_SCOPE_AGENT);
            v2 = __hip_atomic_load(rbuf + tid + 512, __ATOMIC_RELAXED, __HIP_MEMORY_SCOPE_AGENT);
            v3 = __hip_atomic_load(rbuf + tid + 768, __ATOMIC_RELAXED, __HIP_MEMORY_SCOPE_AGENT);
            v4 = __hip_atomic_load(rbuf + tid + 1024, __ATOMIC_RELAXED, __HIP_MEMORY_SCOPE_AGENT);
            v5 = __hip_atomic_load(rbuf + tid + 1280, __ATOMIC_RELAXED, __HIP_MEMORY_SCOPE_AGENT);
            bool ok = ((unsigned)(v0 >> 32) == want) & ((unsigned)(v1 >> 32) == want) &
                      ((unsigned)(v2 >> 32) == want) & ((unsigned)(v3 >> 32) == want) &
                      ((unsigned)(v4 >> 32) == want) & ((unsigned)(v5 >> 32) == want);
            if (ok) break;
        }
        {
            ull vv[6] = {v0, v1, v2, v3, v4, v5};
#pragma unroll
            for (int k = 0; k < 6; ++k) {
                int i = tid + k * 256;
                int bb2 = i / 768, uu = i - bb2 * 768;
                hs[bb2][uu] = __uint_as_float((unsigned)vv[k]);
            }
        }
        __syncthreads();                       // hs(s) ready
        // capture old-h + prefetch gi for the finisher (hidden under FMA)
        float hold = 0.f, g0 = 0.f, g1 = 0.f, g2 = 0.f;
        if (tid < 32) {
            int c = u0 + (tid & 15);
            hold = hs[tid >> 4][c];
            long row = (long)(bp * 2 + (tid >> 4)) * 270 + s;
            const float* gp = gi + row * H3;
            g0 = gp[c];
            g1 = gp[H_ + c];
            g2 = gp[2 * H_ + c];
        }
        float ar = 0.f, az = 0.f, an = 0.f;
        const float* hb = &hs[b2][0];
#pragma unroll 4
        for (int i = 0; i < 24; ++i) {
            int k4 = i * 8 + q;
            f32x4 hv = *(const f32x4*)(hb + k4 * 4);
            f32x4 wr = wsv[k4 * 16 + u];
            f32x4 wz = wsv[(192 + k4) * 16 + u];
            f32x4 wn = wsv[(384 + k4) * 16 + u];
            ar += hv.x * wr.x + hv.y * wr.y + hv.z * wr.z + hv.w * wr.w;
            az += hv.x * wz.x + hv.y * wz.y + hv.z * wz.z + hv.w * wz.w;
            an += hv.x * wn.x + hv.y * wn.y + hv.z * wn.z + hv.w * wn.w;
        }
        int oi = (b2 << 4) | u;
        part[q][oi][0] = ar;
        part[q][oi][1] = az;
        part[q][oi][2] = an;
        __syncthreads();                       // partials ready; hs reads done
        if (tid < 32) {
            float gr = b_r, gz = b_z, gn = b_n;
#pragma unroll
            for (int qq = 0; qq < 8; ++qq) {
                gr += part[qq][tid][0];
                gz += part[qq][tid][1];
                gn += part[qq][tid][2];
            }
            int c = u0 + (tid & 15);
            int bb = bp * 2 + (tid >> 4);
            long row = (long)bb * 270 + s;
            float rg = 1.f / (1.f + expf(-(g0 + gr)));
            float zg = 1.f / (1.f + expf(-(g1 + gz)));
            float ng = tanhf(g2 + rg * gn);
            float hnew = (1.f - zg) * ng + zg * hold;
            ull wv = ((ull)(unsigned)(s + 1) << 32) | (ull)__float_as_uint(hnew);
            __hip_atomic_store(wbuf + (bb & 1) * 768 + c, wv,
                               __ATOMIC_RELAXED, __HIP_MEMORY_SCOPE_AGENT);
            f16 hi16 = (f16)hnew;
            Hhi[row * H_ + c] = hi16;
            Hlo[row * H_ + c] = (f16)(hnew - (float)hi16);
        }
        // no barrier: stores drain while everyone polls the next step
    }
}

// ---------------------------------------------------------------- attention softmax
__global__ __launch_bounds__(256) void k_attn_softmax(const float* __restrict__ lg,
                                                      const int* __restrict__ x, f16* __restrict__ ah) {
    __shared__ float red[256];
    int r = blockIdx.x, tid = threadIdx.x;
    int b = r / 270;
    const float* lr = lg + (long)r * S_;
    const int* xb = x + (long)b * S_;
    float v0 = lr[tid];
    if (xb[tid] == 0) v0 = -1e9f;
    float v1 = lr[tid + 256];
    if (xb[tid + 256] == 0) v1 = -1e9f;
    red[tid] = fmaxf(v0, v1);
    __syncthreads();
    for (int o = 128; o > 0; o >>= 1) {
        if (tid < o) red[tid] = fmaxf(red[tid], red[tid + o]);
        __syncthreads();
    }
    float m = red[0];
    __syncthreads();
    float e0 = __expf(v0 - m), e1 = __expf(v1 - m);
    red[tid] = e0 + e1;
    __syncthreads();
    for (int o = 128; o > 0; o >>= 1) {
        if (tid < o) red[tid] += red[tid + o];
        __syncthreads();
    }
    float inv = 1.f / red[0];
    ah[(long)r * S_ + tid] = (f16)(e0 * inv);
    ah[(long)r * S_ + tid + 256] = (f16)(e1 * inv);
}

// ---------------------------------------------------------------- p_gen
__global__ __launch_bounds__(256) void k_pgen(const f16* __restrict__ Wall, const f16* __restrict__ Hhi,
                                              const f16* __restrict__ Hlo, const float* __restrict__ ctx,
                                              const float* __restrict__ wg, const float* __restrict__ wgb,
                                              float* __restrict__ pg) {
    __shared__ float red[256];
    int r = blockIdx.x, tid = threadIdx.x;
    float a = 0.f;
    for (int i = tid; i < H_; i += 256) {
        a += (float)Wall[(long)r * H_ + i] * wg[i];
        a += ((float)Hhi[(long)r * H_ + i] + (float)Hlo[(long)r * H_ + i]) * wg[H_ + i];
        a += ctx[(long)r * H_ + i] * wg[2 * H_ + i];
    }
    red[tid] = a;
    __syncthreads();
    for (int o = 128; o > 0; o >>= 1) {
        if (tid < o) red[tid] += red[tid + o];
        __syncthreads();
    }
    if (tid == 0) pg[r] = 1.f / (1.f + expf(-(red[0] + wgb[0])));
}

// ---------------------------------------------------------------- vocab softmax stats (online)
__global__ __launch_bounds__(256) void k_rowstat(const float* __restrict__ out, float* __restrict__ rm,
                                                 float* __restrict__ rinv) {
    __shared__ float rm_s[256], rs_s[256];
    int r = blockIdx.x, tid = threadIdx.x;
    const f32x4* p = (const f32x4*)(out + (long)r * V_);
    float m = -3e38f, ssum = 0.f;
    for (int i = tid; i < V_ / 4; i += 256) {
        f32x4 v = p[i];
        float mv = fmaxf(fmaxf(v.x, v.y), fmaxf(v.z, v.w));
        if (mv > m) {
            ssum *= __expf(m - mv);
            m = mv;
        }
        ssum += __expf(v.x - m) + __expf(v.y - m) + __expf(v.z - m) + __expf(v.w - m);
    }
    rm_s[tid] = m;
    rs_s[tid] = ssum;
    __syncthreads();
    for (int o = 128; o > 0; o >>= 1) {
        if (tid < o) {
            float m2 = rm_s[tid + o], s2 = rs_s[tid + o];
            float M = fmaxf(rm_s[tid], m2);
            rs_s[tid] = rs_s[tid] * __expf(rm_s[tid] - M) + s2 * __expf(m2 - M);
            rm_s[tid] = M;
        }
        __syncthreads();
    }
    if (tid == 0) {
        rm[r] = rm_s[0];
        rinv[r] = 1.f / rs_s[0];
    }
}

// ---------------------------------------------------------------- finalize: p_gen * softmax (in place)
__global__ __launch_bounds__(256) void k_final(float* __restrict__ out, const float* __restrict__ rm,
                                               const float* __restrict__ rinv, const float* __restrict__ pg) {
    int r = blockIdx.y;
    int i = blockIdx.x * 256 + threadIdx.x;
    if (i >= V_ / 4) return;
    float m = rm[r], inv = rinv[r], p = pg[r];
    f32x4* po = (f32x4*)(out + (long)r * V_);
    f32x4 v = po[i];
    v.x = p * __expf(v.x - m) * inv;
    v.y = p * __expf(v.y - m) * inv;
    v.z = p * __expf(v.z - m) * inv;
    v.w = p * __expf(v.w - m) * inv;
    po[i] = v;
}

// ---------------------------------------------------------------- pointer scatter
__global__ __launch_bounds__(512) void k_scatter(float* __restrict__ out, const f16* __restrict__ ah,
                                                 const float* __restrict__ pg, const int* __restrict__ x) {
    int r = blockIdx.x, s = threadIdx.x;
    int b = r / 270;
    int xv = x[(long)b * S_ + s];
    if (xv == 0) return;
    float a = (float)ah[(long)r * S_ + s];
    if (a == 0.f) return;
    atomicAdd(out + (long)r * V_ + xv, (1.f - pg[r]) * a);
}

// ---------------------------------------------------------------- host
extern "C" void kernel_launch(void* const* d_in, const int* in_sizes, int n_in, void* d_out,
                              int out_size, void* d_ws, size_t ws_size, hipStream_t stream) {
    (void)in_sizes; (void)n_in; (void)out_size; (void)ws_size;
    const int* x = (const int*)d_in[0];
    const float* dec = (const float*)d_in[1];
    const float* enc = (const float*)d_in[2];
    const float* hid = (const float*)d_in[3];
    const int* tea = (const int*)d_in[4];
    const float* emb = (const float*)d_in[6];
    const float* wih = (const float*)d_in[7];
    const float* whh = (const float*)d_in[8];
    const float* bih = (const float*)d_in[9];
    const float* bhh = (const float*)d_in[10];
    const float* wgw = (const float*)d_in[11];
    const float* wgb = (const float*)d_in[12];
    float* out = (float*)d_out;

    char* w = (char*)d_ws;
    size_t off = 0;
    auto alloc = [&](size_t bytes) {
        void* p = w + off;
        off = (off + bytes + 255) & ~(size_t)255;
        return p;
    };
    ull* hbuf = (ull*)alloc(2 * NGRP * 1536 * 8);   // [parity][pair][1536] seq-tagged h
    f16* Wall = (f16*)alloc((size_t)R_ * H_ * 2);
    f16* wih16 = (f16*)alloc((size_t)H3 * H_ * 2);
    float* giA = (float*)alloc((size_t)R_ * H3 * 4);
    f16* Hhi = (f16*)alloc((size_t)R_ * H_ * 2);
    f16* Hlo = (f16*)alloc((size_t)R_ * H_ * 2);
    f16* emb16 = (f16*)alloc((size_t)V_ * H_ * 2);
    f16* ehi = (f16*)alloc((size_t)B_ * S_ * H_ * 2);
    f16* elo = (f16*)alloc((size_t)B_ * S_ * H_ * 2);
    f16* encT = (f16*)alloc((size_t)B_ * H_ * S_ * 2);
    float* lgH = (float*)alloc((size_t)R_ * S_ * 4);
    f16* ah = (f16*)alloc((size_t)R_ * S_ * 2);
    float* ctx = (float*)alloc((size_t)R_ * H_ * 4);
    float* pg = (float*)alloc(R_ * 4);
    float* rm = (float*)alloc(R_ * 4);
    float* rinv = (float*)alloc(R_ * 4);

    const int nH = 2 * NGRP * 1536 * 2;             // hbuf as ints
    k_zero<<<(nH + 255) / 256, 256, 0, stream>>>((int*)hbuf, nH);
    k_cast<<<2048, 256, 0, stream>>>(emb, emb16, (long)V_ * H_);
    k_cast<<<512, 256, 0, stream>>>(wih, wih16, (long)H3 * H_);
    k_build_wall<<<R_, 256, 0, stream>>>(emb, dec, tea, Wall);
    k_build_enc<<<1024, 256, 0, stream>>>(enc, ehi, elo, encT);
    k_init_h<<<24, 256, 0, stream>>>(hid, hbuf);

    // gi = W_all @ w_ih^T + b_ih
    {
        dim3 g(H3 / 128, (R_ + 127) / 128, 1);
        k_gemm<1><<<g, 256, 0, stream>>>(Wall, wih16, giA, bih, R_, H3, H_, 0, 0, 0);
    }
    k_gru<<<NGRP * GBLK, 256, 0, stream>>>(giA, whh, bhh, hbuf, Hhi, Hlo);

    // attention logits, hi/lo split: Hhi*Ehi + Hhi*Elo + Hlo*Ehi
    {
        dim3 g(S_ / 128, 3, 8);
        k_gemm<0><<<g, 256, 0, stream>>>(Hhi, ehi, lgH, nullptr, 270, S_, H_, 270L * H_, (long)S_ * H_, 270L * S_);
        k_gemm<2><<<g, 256, 0, stream>>>(Hhi, elo, lgH, nullptr, 270, S_, H_, 270L * H_, (long)S_ * H_, 270L * S_);
        k_gemm<2><<<g, 256, 0, stream>>>(Hlo, ehi, lgH, nullptr, 270, S_, H_, 270L * H_, (long)S_ * H_, 270L * S_);
    }
    k_attn_softmax<<<R_, 256, 0, stream>>>(lgH, x, ah);
    {
        dim3 g(H_ / 128, 3, 8);
        k_gemm<0><<<g, 256, 0, stream>>>(ah, encT, ctx, nullptr, 270, H_, S_, 270L * S_, (long)H_ * S_, 270L * H_);
    }
    k_pgen<<<R_, 256, 0, stream>>>(Wall, Hhi, Hlo, ctx, wgw, wgb, pg);

    // vocab logits straight into d_out
    {
        dim3 g((V_ + 127) / 128, (R_ + 127) / 128, 1);
        k_gemm<0><<<g, 256, 0, stream>>>(Hhi, emb16, out, nullptr, R_, V_, H_, 0, 0, 0);
    }
    k_rowstat<<<R_, 256, 0, stream>>>(out, rm, rinv);
    {
        dim3 g((V_ / 4 + 255) / 256, R_, 1);
        k_final<<<g, 256, 0, stream>>>(out, rm, rinv, pg);
    }
    k_scatter<<<R_, 512, 0, stream>>>(out, ah, pg, x);
}